// Round 14
// baseline (220.683 us; speedup 1.0000x reference)
//
#include <hip/hip_runtime.h>
#include <hip/hip_bf16.h>

#define B_ 2
#define T_ 2048
#define C_ 2048
#define H_ 16
#define KH_ 4
#define D_ 128

typedef unsigned short ushort_t;
typedef __attribute__((ext_vector_type(8))) short short8;
typedef __attribute__((ext_vector_type(4))) float f32x4;

#define RSQRT_D 0.08838834764831845f
#define L2E 1.4426950408889634f
// Q pre-scale: 1/sqrt(D) * log2(e)  ->  QK^T lands in log2 units, softmax is pure exp2
#define QSCALE (0.08838834764831845f * 1.4426950408889634f)

__device__ __forceinline__ ushort_t f2b(float f) {
  union { float f; unsigned u; } v; v.f = f;
  unsigned r = v.u + 0x7fffu + ((v.u >> 16) & 1u);
  return (ushort_t)(r >> 16);
}
__device__ __forceinline__ float b2f(ushort_t u) {
  union { unsigned u; float f; } v; v.u = ((unsigned)u) << 16;
  return v.f;
}

__device__ __forceinline__ f32x4 mfma16(short8 a, short8 b, f32x4 c) {
  return __builtin_amdgcn_mfma_f32_16x16x32_bf16(a, b, c, 0, 0, 0);
}

__device__ __forceinline__ void async16(const void* g, void* l) {
  __builtin_amdgcn_global_load_lds(
      (const __attribute__((address_space(1))) void*)g,
      (__attribute__((address_space(3))) void*)l, 16, 0, 0);
}

// packed f32x2 -> bf16x2 (RTNE); dst.lo = bf16(lo), dst.hi = bf16(hi)
__device__ __forceinline__ unsigned cvtpk(float lo, float hi) {
  unsigned r;
  asm volatile("v_cvt_pk_bf16_f32 %0, %1, %2" : "=v"(r) : "v"(lo), "v"(hi));
  return r;
}

// ---------------- small prep kernels ----------------

__global__ void convert_f32_bf16(const float* __restrict__ in, ushort_t* __restrict__ out, int n4) {
  int i = blockIdx.x * blockDim.x + threadIdx.x;
  if (i >= n4) return;
  float4 v = ((const float4*)in)[i];
  ushort4 o;
  o.x = f2b(v.x); o.y = f2b(v.y); o.z = f2b(v.z); o.w = f2b(v.w);
  ((ushort4*)out)[i] = o;
}

// out[c][r] = bf16(in[r][c]);  in: R x C f32, out: C x R bf16
__global__ void transpose_to_bf16(const float* __restrict__ in, ushort_t* __restrict__ out, int R, int C) {
  __shared__ float tile[32][33];
  int c0 = blockIdx.x * 32, r0 = blockIdx.y * 32;
  int tx = threadIdx.x, ty = threadIdx.y;
#pragma unroll
  for (int i = 0; i < 4; i++) {
    int r = ty + i * 8;
    tile[r][tx] = in[(size_t)(r0 + r) * C + c0 + tx];
  }
  __syncthreads();
#pragma unroll
  for (int i = 0; i < 4; i++) {
    int r = ty + i * 8;
    out[(size_t)(c0 + r) * R + r0 + tx] = f2b(tile[tx][r]);
  }
}

// cos/sin table: tab[t*64+d] = (cos(t*omega[d]), sin(t*omega[d]))
__global__ void rope_tab_k(const float* __restrict__ omega, float2* __restrict__ tab) {
  int idx = blockIdx.x * blockDim.x + threadIdx.x;  // 2048*64
  int d = idx & 63;
  int t = idx >> 6;
  float ang = (float)t * omega[d];
  tab[idx] = make_float2(cosf(ang), sinf(ang));
}

// QKVraw [b*T+t][3072]: cols 0..2047 = q -> rope (pre-scaled by QSCALE)
// vectorized x4: thread handles d = d4..d4+3 (and +64 pair)
__global__ void rope_q_k(const ushort_t* __restrict__ QKVraw, const float2* __restrict__ tab,
                         ushort_t* __restrict__ Qb) {
  int idx = blockIdx.x * blockDim.x + threadIdx.x;  // B*T*H*16 = 1048576
  int d4 = (idx & 15) * 4;
  int h = (idx >> 4) & 15;
  int t = (idx >> 8) & 2047;
  int b = idx >> 19;
  size_t in_off = (size_t)(b * 2048 + t) * 3072 + h * 128 + d4;
  ushort4 x1 = *(const ushort4*)(QKVraw + in_off);
  ushort4 x2 = *(const ushort4*)(QKVraw + in_off + 64);
  float4 csA = *(const float4*)(&tab[t * 64 + d4]);      // c0 s0 c1 s1
  float4 csB = *(const float4*)(&tab[t * 64 + d4 + 2]);  // c2 s2 c3 s3
  ushort4 o1, o2;
  o1.x = f2b((b2f(x1.x) * csA.x - b2f(x2.x) * csA.y) * QSCALE);
  o2.x = f2b((b2f(x1.x) * csA.y + b2f(x2.x) * csA.x) * QSCALE);
  o1.y = f2b((b2f(x1.y) * csA.z - b2f(x2.y) * csA.w) * QSCALE);
  o2.y = f2b((b2f(x1.y) * csA.w + b2f(x2.y) * csA.z) * QSCALE);
  o1.z = f2b((b2f(x1.z) * csB.x - b2f(x2.z) * csB.y) * QSCALE);
  o2.z = f2b((b2f(x1.z) * csB.y + b2f(x2.z) * csB.x) * QSCALE);
  o1.w = f2b((b2f(x1.w) * csB.z - b2f(x2.w) * csB.w) * QSCALE);
  o2.w = f2b((b2f(x1.w) * csB.w + b2f(x2.w) * csB.z) * QSCALE);
  size_t out_off = ((size_t)(b * 16 + h) * 2048 + t) * 128 + d4;
  *(ushort4*)(Qb + out_off) = o1;
  *(ushort4*)(Qb + out_off + 64) = o2;
}

// QKVraw cols 2048..2559 = k -> rope -> Kb [(b*4+kh)*T + t][d], vectorized x4
__global__ void rope_k_k(const ushort_t* __restrict__ QKVraw, const float2* __restrict__ tab,
                         ushort_t* __restrict__ Kb) {
  int idx = blockIdx.x * blockDim.x + threadIdx.x;  // B*T*KH*16 = 262144
  int d4 = (idx & 15) * 4;
  int kh = (idx >> 4) & 3;
  int t = (idx >> 6) & 2047;
  int b = idx >> 17;
  size_t in_off = (size_t)(b * 2048 + t) * 3072 + 2048 + kh * 128 + d4;
  ushort4 x1 = *(const ushort4*)(QKVraw + in_off);
  ushort4 x2 = *(const ushort4*)(QKVraw + in_off + 64);
  float4 csA = *(const float4*)(&tab[t * 64 + d4]);
  float4 csB = *(const float4*)(&tab[t * 64 + d4 + 2]);
  ushort4 o1, o2;
  o1.x = f2b(b2f(x1.x) * csA.x - b2f(x2.x) * csA.y);
  o2.x = f2b(b2f(x1.x) * csA.y + b2f(x2.x) * csA.x);
  o1.y = f2b(b2f(x1.y) * csA.z - b2f(x2.y) * csA.w);
  o2.y = f2b(b2f(x1.y) * csA.w + b2f(x2.y) * csA.z);
  o1.z = f2b(b2f(x1.z) * csB.x - b2f(x2.z) * csB.y);
  o2.z = f2b(b2f(x1.z) * csB.y + b2f(x2.z) * csB.x);
  o1.w = f2b(b2f(x1.w) * csB.z - b2f(x2.w) * csB.w);
  o2.w = f2b(b2f(x1.w) * csB.w + b2f(x2.w) * csB.z);
  size_t out_off = ((size_t)(b * 4 + kh) * 2048 + t) * 128 + d4;
  *(ushort4*)(Kb + out_off) = o1;
  *(ushort4*)(Kb + out_off + 64) = o2;
}

// V fragment pre-pack: Vf short8 index = (((z*32+tile)*2+hv)*8+n)*64 + lane
// element j = V[b][t = tile*64 + kl][kh][d = n*16 + (lane&15)]
// kl = (hv*2 + ((j>>1)>>1))*16 + (lane>>4)*4 + 2*((j>>1)&1) + (j&1)
__global__ void v_frag_k(const ushort_t* __restrict__ QKVraw, ushort_t* __restrict__ Vf) {
  int idx = blockIdx.x * blockDim.x + threadIdx.x;  // 262144 short8 units
  int lane = idx & 63;
  int n = (idx >> 6) & 7;
  int hv = (idx >> 9) & 1;
  int tile = (idx >> 10) & 31;
  int z = idx >> 15;  // b*4+kh
  int b = z >> 2, kh = z & 3;
  int lr = lane & 15, lc = lane >> 4;
  int d = n * 16 + lr;
  union { ushort_t u[8]; short8 v; } out;
#pragma unroll
  for (int j = 0; j < 8; j++) {
    int tw = j >> 1, par = j & 1;
    int kl = (hv * 2 + (tw >> 1)) * 16 + lc * 4 + 2 * (tw & 1) + par;
    int t = tile * 64 + kl;
    out.u[j] = QKVraw[(size_t)(b * 2048 + t) * 3072 + 2560 + kh * 128 + d];
  }
  *(short8*)(Vf + (size_t)idx * 8) = out.v;
}

__device__ __forceinline__ void store_out(float* C, size_t idx, float v) { C[idx] = v; }
__device__ __forceinline__ void store_out(ushort_t* C, size_t idx, float v) { C[idx] = f2b(v); }

// ---------------- GEMM 256xBN 8-phase: counted vmcnt, m201 order, 100% CU fill ----
// NF = per-wave 16-col fragments (3 -> BN=192 for QKV, 2 -> BN=128 for proj).
// BM=256, BK=64 as k0/k1 halves. 512 thr = 8 waves (2M x 4N); per-wave C =
// 128 x NF*16 (acc[8][NF]). Every STAGE = exactly 2 async16/thread (B's
// NF*256 units: load0 all threads; load1 real for tid < NF*256-512 else a
// dummy into scratch) so the counted-vmcnt constants are schedule-invariant.
// Phase = { ds_read subtile ; STAGE one t+1 half ; barrier ; lgkmcnt(0) ;
// setprio(1) MFMA setprio(0) ; [vmcnt(4) at P1/P3] ; barrier }.
// Swizzle: chunk = lc ^ ((row>>1)&3), source pre-swizzled (both-sides).
// Grid: 1D 256 blocks (=1/CU), XCD-bijective swizzle (256 % 8 == 0).
template <int NF, typename OUT_T>
__global__ __launch_bounds__(512, 1) void gemm256(const ushort_t* __restrict__ A,
                                                  const ushort_t* __restrict__ Bt,
                                                  OUT_T* __restrict__ C,
                                                  int M, int N, int K) {
  __shared__ __attribute__((aligned(16))) ushort_t As[2][2][8192];
  __shared__ __attribute__((aligned(16))) ushort_t Bs[2][2][NF * 2048];
  __shared__ __attribute__((aligned(16))) ushort_t Scr[512];
  const int tid = threadIdx.x;
  const int lane = tid & 63;
  const int w = tid >> 6;          // 0..7
  const int lr = lane & 15, lc = lane >> 4;
  const int wm = w >> 2, wn = w & 3;
  // XCD-aware bijective swizzle over 1D grid
  const int nwg = gridDim.x;
  const int cpx = nwg >> 3;
  const int swz = (blockIdx.x & 7) * cpx + (blockIdx.x >> 3);
  const int bnc = N / (NF * 64);
  const int bm = swz / bnc, bn = swz % bnc;
  const ushort_t* Ab = A + (size_t)bm * 256 * K;
  const ushort_t* Bb = Bt + (size_t)bn * (NF * 64) * K;

  f32x4 acc[8][NF];
#pragma unroll
  for (int i = 0; i < 8; i++)
#pragma unroll
    for (int j = 0; j < NF; j++) acc[i][j] = (f32x4)(0.0f);

  auto STAGE = [&](int kt, int hid) {
    const int buf = kt & 1;
    const int kk = hid >> 1;
    const int kbase = kt * 64 + kk * 32;
    if (!(hid & 1)) {
      // A half: 1024 units; u0 = tid, u1 = 512 + tid
      ushort_t* db = &As[buf][kk][0];
      {
        const int u = tid, row = u >> 2, c = u & 3;
        const int lch = c ^ ((row >> 1) & 3);
        async16(Ab + (size_t)row * K + kbase + lch * 8, db + u * 8);
      }
      {
        const int u = 512 + tid, row = u >> 2, c = u & 3;
        const int lch = c ^ ((row >> 1) & 3);
        async16(Ab + (size_t)row * K + kbase + lch * 8, db + u * 8);
      }
    } else {
      // B half: NF*256 units; load0 = all threads, load1 real for tid<NF*256-512
      ushort_t* db = &Bs[buf][kk][0];
      {
        const int u = tid, row = u >> 2, c = u & 3;
        const int lch = c ^ ((row >> 1) & 3);
        async16(Bb + (size_t)row * K + kbase + lch * 8, db + u * 8);
      }
      if (NF * 256 - 512 > 0 && tid < NF * 256 - 512) {
        const int u = 512 + tid, row = u >> 2, c = u & 3;
        const int lch = c ^ ((row >> 1) & 3);
        async16(Bb + (size_t)row * K + kbase + lch * 8, db + u * 8);
      } else {
        // dummy keeps per-wave vmcnt counts uniform; Scr never read
        async16(Bb + (size_t)(tid & 255) * 8, &Scr[0]);
      }
    }
  };

  const int nt = K >> 6;
  // prologue: stage tile0 fully; publish A_k0/B_k0 (keep A_k1/B_k1 in flight)
  STAGE(0, 0); STAGE(0, 1); STAGE(0, 2); STAGE(0, 3);
  asm volatile("s_waitcnt vmcnt(4)" ::: "memory");
  __builtin_amdgcn_s_barrier();

#pragma unroll 1
  for (int t = 0; t < nt; ++t) {
    const int buf = t & 1;
    const ushort_t* Ak0 = &As[buf][0][0];
    const ushort_t* Ak1 = &As[buf][1][0];
    const ushort_t* Bk0 = &Bs[buf][0][0];
    const ushort_t* Bk1 = &Bs[buf][1][0];
    short8 af[4], bf[NF];

    // ---- P0: ds B_k0 + A[mq0,k0]; stage t+1.A_k0
#pragma unroll
    for (int nf = 0; nf < NF; nf++) {
      const int row = wn * (NF * 16) + nf * 16 + lr;
      bf[nf] = *(const short8*)(Bk0 + row * 32 + ((lc ^ ((row >> 1) & 3)) * 8));
    }
#pragma unroll
    for (int mf = 0; mf < 4; mf++) {
      const int row = wm * 128 + mf * 16 + lr;
      af[mf] = *(const short8*)(Ak0 + row * 32 + ((lc ^ ((row >> 1) & 3)) * 8));
    }
    if (t + 1 < nt) STAGE(t + 1, 0);
    __builtin_amdgcn_s_barrier();
    asm volatile("s_waitcnt lgkmcnt(0)" ::: "memory");
    __builtin_amdgcn_sched_barrier(0);
    __builtin_amdgcn_s_setprio(1);
#pragma unroll
    for (int mf = 0; mf < 4; mf++)
#pragma unroll
      for (int nf = 0; nf < NF; nf++)
        acc[mf][nf] = mfma16(af[mf], bf[nf], acc[mf][nf]);
    __builtin_amdgcn_s_setprio(0);
    __builtin_amdgcn_s_barrier();

    // ---- P1: ds A[mq1,k0]; stage t+1.B_k0; MFMA; vmcnt publishes A_k1/B_k1
#pragma unroll
    for (int mf = 0; mf < 4; mf++) {
      const int row = wm * 128 + 64 + mf * 16 + lr;
      af[mf] = *(const short8*)(Ak0 + row * 32 + ((lc ^ ((row >> 1) & 3)) * 8));
    }
    if (t + 1 < nt) STAGE(t + 1, 1);
    __builtin_amdgcn_s_barrier();
    asm volatile("s_waitcnt lgkmcnt(0)" ::: "memory");
    __builtin_amdgcn_sched_barrier(0);
    __builtin_amdgcn_s_setprio(1);
#pragma unroll
    for (int mf = 0; mf < 4; mf++)
#pragma unroll
      for (int nf = 0; nf < NF; nf++)
        acc[4 + mf][nf] = mfma16(af[mf], bf[nf], acc[4 + mf][nf]);
    __builtin_amdgcn_s_setprio(0);
    if (t + 1 < nt) {
      asm volatile("s_waitcnt vmcnt(4)" ::: "memory");
    } else {
      asm volatile("s_waitcnt vmcnt(0)" ::: "memory");
    }
    __builtin_amdgcn_s_barrier();

    // ---- P2: ds B_k1 + A[mq0,k1]; stage t+1.A_k1; MFMA
#pragma unroll
    for (int nf = 0; nf < NF; nf++) {
      const int row = wn * (NF * 16) + nf * 16 + lr;
      bf[nf] = *(const short8*)(Bk1 + row * 32 + ((lc ^ ((row >> 1) & 3)) * 8));
    }
#pragma unroll
    for (int mf = 0; mf < 4; mf++) {
      const int row = wm * 128 + mf * 16 + lr;
      af[mf] = *(const short8*)(Ak1 + row * 32 + ((lc ^ ((row >> 1) & 3)) * 8));
    }
    if (t + 1 < nt) STAGE(t + 1, 2);
    __builtin_amdgcn_s_barrier();
    asm volatile("s_waitcnt lgkmcnt(0)" ::: "memory");
    __builtin_amdgcn_sched_barrier(0);
    __builtin_amdgcn_s_setprio(1);
#pragma unroll
    for (int mf = 0; mf < 4; mf++)
#pragma unroll
      for (int nf = 0; nf < NF; nf++)
        acc[mf][nf] = mfma16(af[mf], bf[nf], acc[mf][nf]);
    __builtin_amdgcn_s_setprio(0);
    __builtin_amdgcn_s_barrier();

    // ---- P3: ds A[mq1,k1]; stage t+1.B_k1; MFMA; vmcnt publishes t+1 A_k0/B_k0
#pragma unroll
    for (int mf = 0; mf < 4; mf++) {
      const int row = wm * 128 + 64 + mf * 16 + lr;
      af[mf] = *(const short8*)(Ak1 + row * 32 + ((lc ^ ((row >> 1) & 3)) * 8));
    }
    if (t + 1 < nt) STAGE(t + 1, 3);
    __builtin_amdgcn_s_barrier();
    asm volatile("s_waitcnt lgkmcnt(0)" ::: "memory");
    __builtin_amdgcn_sched_barrier(0);
    __builtin_amdgcn_s_setprio(1);
#pragma unroll
    for (int mf = 0; mf < 4; mf++)
#pragma unroll
      for (int nf = 0; nf < NF; nf++)
        acc[4 + mf][nf] = mfma16(af[mf], bf[nf], acc[4 + mf][nf]);
    __builtin_amdgcn_s_setprio(0);
    if (t + 1 < nt) {
      asm volatile("s_waitcnt vmcnt(4)" ::: "memory");
    }
    __builtin_amdgcn_s_barrier();
  }

#pragma unroll
  for (int mfp = 0; mfp < 8; mfp++) {
#pragma unroll
    for (int nf = 0; nf < NF; nf++) {
      const int row = bm * 256 + wm * 128 + mfp * 16 + lc * 4;
      const int col = bn * (NF * 64) + wn * (NF * 16) + nf * 16 + lr;
#pragma unroll
      for (int r = 0; r < 4; r++)
        store_out(C, (size_t)(row + r) * N + col, acc[mfp][nf][r]);
    }
  }
}

// ---------------- flash attention (causal GQA) — R9 config (best: 76us) ----------------
__global__ __launch_bounds__(256, 2) void attn_k(const ushort_t* __restrict__ Qb,
                                                 const ushort_t* __restrict__ Kb,
                                                 const ushort_t* __restrict__ Vf,
                                                 ushort_t* __restrict__ Yb) {
  __shared__ __attribute__((aligned(16))) ushort_t Ks[2][64 * 128];  // 32 KB
  const int tid = threadIdx.x;
  const int lane = tid & 63;
  const int w = tid >> 6;
  const int lr = lane & 15, lc = lane >> 4;
  const int gy = blockIdx.y;
  const int h = gy;
  const int b = blockIdx.z;
  const int kh = h >> 2;
  const int qc = b ? (15 - ((blockIdx.x + gy) & 15)) : ((blockIdx.x + gy) & 15);
  const int q0w = qc * 128 + w * 32;

  const ushort_t* Qp = Qb + (size_t)(b * 16 + h) * T_ * D_;
  const ushort_t* Kp = Kb + (size_t)(b * 4 + kh) * T_ * D_;
  const ushort_t* Vfb = Vf + (size_t)(b * 4 + kh) * 262144;

  const int st_row = tid >> 4;
  const int st_slot = tid & 15;

  short8 qf[2][4];
#pragma unroll
  for (int f = 0; f < 2; f++)
#pragma unroll
    for (int c = 0; c < 4; c++)
      qf[f][c] = *(const short8*)(Qp + (size_t)(q0w + f * 16 + lr) * D_ + c * 32 + lc * 8);

  f32x4 o[2][8];
#pragma unroll
  for (int f = 0; f < 2; f++)
#pragma unroll
    for (int n = 0; n < 8; n++) o[f][n] = (f32x4)(0.0f);
  float m[2] = {-1e30f, -1e30f}, l[2] = {0.0f, 0.0f};

  const int nt = 2 * qc + 2;

#pragma unroll
  for (int i = 0; i < 4; i++) {
    int row = i * 16 + st_row;
    async16(Kp + (size_t)row * D_ + (((st_slot - row) & 15) * 8),
            &Ks[0][0] + row * 128 + st_slot * 8);
  }

#pragma unroll 1
  for (int ti = 0; ti < nt; ti++) {
    __syncthreads();
    const int kv0 = ti * 64;
    if (ti + 1 < nt) {
      const ushort_t* Kn = Kp + (size_t)(kv0 + 64) * D_;
      ushort_t* dst = &Ks[(ti + 1) & 1][0];
#pragma unroll
      for (int i = 0; i < 4; i++) {
        int row = i * 16 + st_row;
        async16(Kn + (size_t)row * D_ + (((st_slot - row) & 15) * 8),
                dst + row * 128 + st_slot * 8);
      }
    }
    if (kv0 > q0w + 31) continue;
    const ushort_t* Kl = &Ks[ti & 1][0];
    const ushort_t* Vt0 = Vfb + (size_t)(ti * 2) * 4096;
    short8 vr0[8];
#pragma unroll
    for (int n = 0; n < 8; n++)
      vr0[n] = *(const short8*)(Vt0 + n * 512 + lane * 8);
    f32x4 s[2][4];
#pragma unroll
    for (int f = 0; f < 2; f++)
#pragma unroll
      for (int kj = 0; kj < 4; kj++) s[f][kj] = (f32x4)(0.0f);
    __builtin_amdgcn_s_setprio(1);
#pragma unroll
    for (int c = 0; c < 4; c++) {
      short8 kf[4];
#pragma unroll
      for (int kj = 0; kj < 4; kj++)
        kf[kj] = *(const short8*)(Kl + (kj * 16 + lr) * 128 + (((c * 4 + lc + lr) & 15) * 8));
#pragma unroll
      for (int f = 0; f < 2; f++)
#pragma unroll
        for (int kj = 0; kj < 4; kj++)
          s[f][kj] = mfma16(kf[kj], qf[f][c], s[f][kj]);
    }
    __builtin_amdgcn_s_setprio(0);
    const ushort_t* Vt1 = Vfb + (size_t)(ti * 2 + 1) * 4096;
    short8 vr1[8];
#pragma unroll
    for (int n = 0; n < 8; n++)
      vr1[n] = *(const short8*)(Vt1 + n * 512 + lane * 8);
    const bool maskt = (kv0 + 63 > q0w);
    union { unsigned u[4]; short8 v; } pa0[2], pa1[2];
#pragma unroll
    for (int f = 0; f < 2; f++) {
      const int q = q0w + f * 16 + lr;
      float pv[16];
      float mx = -1e30f;
      if (maskt) {
#pragma unroll
        for (int kj = 0; kj < 4; kj++)
#pragma unroll
          for (int r = 0; r < 4; r++) {
            float a = s[f][kj][r];
            if (kv0 + kj * 16 + lc * 4 + r > q) a = -1e30f;
            pv[kj * 4 + r] = a;
            mx = fmaxf(mx, a);
          }
      } else {
#pragma unroll
        for (int kj = 0; kj < 4; kj++)
#pragma unroll
          for (int r = 0; r < 4; r++) {
            float a = s[f][kj][r];
            pv[kj * 4 + r] = a;
            mx = fmaxf(mx, a);
          }
      }
      mx = fmaxf(mx, __shfl_xor(mx, 16));
      mx = fmaxf(mx, __shfl_xor(mx, 32));
      const bool need = __any(mx > m[f] + 8.0f);
      const float mn = need ? fmaxf(m[f], mx) : m[f];
      float rs = 0.0f;
#pragma unroll
      for (int i = 0; i < 16; i++) {
        pv[i] = exp2f(pv[i] - mn);
        rs += pv[i];
      }
      rs += __shfl_xor(rs, 16);
      rs += __shfl_xor(rs, 32);
#pragma unroll
      for (int kj = 0; kj < 2; kj++) {
        pa0[f].u[kj * 2] = cvtpk(pv[kj * 4], pv[kj * 4 + 1]);
        pa0[f].u[kj * 2 + 1] = cvtpk(pv[kj * 4 + 2], pv[kj * 4 + 3]);
        pa1[f].u[kj * 2] = cvtpk(pv[8 + kj * 4], pv[8 + kj * 4 + 1]);
        pa1[f].u[kj * 2 + 1] = cvtpk(pv[8 + kj * 4 + 2], pv[8 + kj * 4 + 3]);
      }
      if (need) {
        float al = exp2f(m[f] - mn);
        m[f] = mn;
        l[f] = l[f] * al + rs;
        float alT[4];
#pragma unroll
        for (int r = 0; r < 4; r++)
          alT[r] = __shfl(al, (lane & 48) | (lc * 4 + r));
#pragma unroll
        for (int n = 0; n < 8; n++)
#pragma unroll
          for (int r = 0; r < 4; r++) o[f][n][r] *= alT[r];
      } else {
        l[f] += rs;
      }
    }
    __builtin_amdgcn_s_setprio(1);
#pragma unroll
    for (int n = 0; n < 8; n++) {
      o[0][n] = mfma16(pa0[0].v, vr0[n], o[0][n]);
      o[1][n] = mfma16(pa0[1].v, vr0[n], o[1][n]);
    }
#pragma unroll
    for (int n = 0; n < 8; n++) {
      o[0][n] = mfma16(pa1[0].v, vr1[n], o[0][n]);
      o[1][n] = mfma16(pa1[1].v, vr1[n], o[1][n]);
    }
    __builtin_amdgcn_s_setprio(0);
  }
#pragma unroll
  for (int f = 0; f < 2; f++) {
    float inv = 1.0f / l[f];
    float invT[4];
#pragma unroll
    for (int r = 0; r < 4; r++)
      invT[r] = __shfl(inv, (lane & 48) | (lc * 4 + r));
#pragma unroll
    for (int n = 0; n < 8; n++)
#pragma unroll
      for (int r = 0; r < 4; r++) {
        int qo = q0w + f * 16 + lc * 4 + r;
        int d = n * 16 + lr;
        Yb[(size_t)(b * T_ + qo) * 2048 + h * 128 + d] = f2b(o[f][n][r] * invT[r]);
      }
  }
}

// ---------------- launch ----------------

extern "C" void kernel_launch(void* const* d_in, const int* in_sizes, int n_in,
                              void* d_out, int out_size, void* d_ws, size_t ws_size,
                              hipStream_t stream) {
  (void)in_sizes; (void)n_in; (void)out_size; (void)ws_size;
  const float* x = (const float*)d_in[0];
  const float* wq = (const float*)d_in[1];
  const float* wkv = (const float*)d_in[2];
  const float* wproj = (const float*)d_in[3];
  const float* omega = (const float*)d_in[4];
  float* out = (float*)d_out;
  char* ws = (char*)d_ws;

  ushort_t* xb     = (ushort_t*)(ws + 0);          // 4096x2048 bf16 = 16.8MB
  ushort_t* wqkvT  = (ushort_t*)(ws + 16777216);   // [3072][2048] bf16 (wqT then wkvT)
  ushort_t* wkvT   = (ushort_t*)(ws + 25165824);   // tail of wqkvT
  ushort_t* wprojT = (ushort_t*)(ws + 29360128);   // 2048x2048 bf16
  ushort_t* QKVraw = (ushort_t*)(ws + 37748736);   // 4096x3072 bf16 = 25.2MB
  ushort_t* Qb     = (ushort_t*)(ws + 62914560);   // [b][h][t][d] bf16
  ushort_t* Kb     = (ushort_t*)(ws + 79691776);   // [b][kh][t][d] bf16
  ushort_t* Vf     = (ushort_t*)(ws + 83886080);   // V fragment-packed, 4MB
  ushort_t* Yb     = (ushort_t*)(ws + 88080384);   // 4096x2048 bf16
  float2*   tab    = (float2*)(ws + 104857600);    // 2048x64 float2 = 1MB

  convert_f32_bf16<<<8192, 256, 0, stream>>>(x, xb, 2097152);
  transpose_to_bf16<<<dim3(64, 64), dim3(32, 8), 0, stream>>>(wq, wqkvT, 2048, 2048);
  transpose_to_bf16<<<dim3(32, 64), dim3(32, 8), 0, stream>>>(wkv, wkvT, 2048, 1024);
  transpose_to_bf16<<<dim3(64, 64), dim3(32, 8), 0, stream>>>(wproj, wprojT, 2048, 2048);
  rope_tab_k<<<512, 256, 0, stream>>>(omega, tab);

  // merged QKV projection via 256x192 8-phase (256 blocks = 100% CU fill)
  gemm256<3><<<256, 512, 0, stream>>>(xb, wqkvT, QKVraw, 4096, 3072, 2048);

  rope_q_k<<<4096, 256, 0, stream>>>(QKVraw, tab, Qb);
  rope_k_k<<<1024, 256, 0, stream>>>(QKVraw, tab, Kb);
  v_frag_k<<<1024, 256, 0, stream>>>(QKVraw, Vf);

  attn_k<<<dim3(16, 16, 2), 256, 0, stream>>>(Qb, Kb, Vf, Yb);

  // output projection via 256x128 8-phase (256 blocks = 100% CU fill)
  gemm256<2><<<256, 512, 0, stream>>>(Yb, wprojT, out, 4096, 2048, 2048);
}

// Round 15
// 220.175 us; speedup vs baseline: 1.0023x; 1.0023x over previous
//
#include <hip/hip_runtime.h>
#include <hip/hip_bf16.h>

#define B_ 2
#define T_ 2048
#define C_ 2048
#define H_ 16
#define KH_ 4
#define D_ 128

typedef unsigned short ushort_t;
typedef __attribute__((ext_vector_type(8))) short short8;
typedef __attribute__((ext_vector_type(4))) float f32x4;

#define RSQRT_D 0.08838834764831845f
#define L2E 1.4426950408889634f
// Q pre-scale: 1/sqrt(D) * log2(e)  ->  QK^T lands in log2 units, softmax is pure exp2
#define QSCALE (0.08838834764831845f * 1.4426950408889634f)

__device__ __forceinline__ ushort_t f2b(float f) {
  union { float f; unsigned u; } v; v.f = f;
  unsigned r = v.u + 0x7fffu + ((v.u >> 16) & 1u);
  return (ushort_t)(r >> 16);
}
__device__ __forceinline__ float b2f(ushort_t u) {
  union { unsigned u; float f; } v; v.u = ((unsigned)u) << 16;
  return v.f;
}

__device__ __forceinline__ f32x4 mfma16(short8 a, short8 b, f32x4 c) {
  return __builtin_amdgcn_mfma_f32_16x16x32_bf16(a, b, c, 0, 0, 0);
}

__device__ __forceinline__ void async16(const void* g, void* l) {
  __builtin_amdgcn_global_load_lds(
      (const __attribute__((address_space(1))) void*)g,
      (__attribute__((address_space(3))) void*)l, 16, 0, 0);
}

// packed f32x2 -> bf16x2 (RTNE); dst.lo = bf16(lo), dst.hi = bf16(hi)
__device__ __forceinline__ unsigned cvtpk(float lo, float hi) {
  unsigned r;
  asm volatile("v_cvt_pk_bf16_f32 %0, %1, %2" : "=v"(r) : "v"(lo), "v"(hi));
  return r;
}

// ---------------- small prep kernels ----------------

__global__ void convert_f32_bf16(const float* __restrict__ in, ushort_t* __restrict__ out, int n4) {
  int i = blockIdx.x * blockDim.x + threadIdx.x;
  if (i >= n4) return;
  float4 v = ((const float4*)in)[i];
  ushort4 o;
  o.x = f2b(v.x); o.y = f2b(v.y); o.z = f2b(v.z); o.w = f2b(v.w);
  ((ushort4*)out)[i] = o;
}

// out[c][r] = bf16(in[r][c]);  in: R x C f32, out: C x R bf16
__global__ void transpose_to_bf16(const float* __restrict__ in, ushort_t* __restrict__ out, int R, int C) {
  __shared__ float tile[32][33];
  int c0 = blockIdx.x * 32, r0 = blockIdx.y * 32;
  int tx = threadIdx.x, ty = threadIdx.y;
#pragma unroll
  for (int i = 0; i < 4; i++) {
    int r = ty + i * 8;
    tile[r][tx] = in[(size_t)(r0 + r) * C + c0 + tx];
  }
  __syncthreads();
#pragma unroll
  for (int i = 0; i < 4; i++) {
    int r = ty + i * 8;
    out[(size_t)(c0 + r) * R + r0 + tx] = f2b(tile[tx][r]);
  }
}

// cos/sin table: tab[t*64+d] = (cos(t*omega[d]), sin(t*omega[d]))
__global__ void rope_tab_k(const float* __restrict__ omega, float2* __restrict__ tab) {
  int idx = blockIdx.x * blockDim.x + threadIdx.x;  // 2048*64
  int d = idx & 63;
  int t = idx >> 6;
  float ang = (float)t * omega[d];
  tab[idx] = make_float2(cosf(ang), sinf(ang));
}

// QKVraw [b*T+t][3072]: cols 0..2047 = q -> rope (pre-scaled by QSCALE)
// vectorized x4: thread handles d = d4..d4+3 (and +64 pair)
__global__ void rope_q_k(const ushort_t* __restrict__ QKVraw, const float2* __restrict__ tab,
                         ushort_t* __restrict__ Qb) {
  int idx = blockIdx.x * blockDim.x + threadIdx.x;  // B*T*H*16 = 1048576
  int d4 = (idx & 15) * 4;
  int h = (idx >> 4) & 15;
  int t = (idx >> 8) & 2047;
  int b = idx >> 19;
  size_t in_off = (size_t)(b * 2048 + t) * 3072 + h * 128 + d4;
  ushort4 x1 = *(const ushort4*)(QKVraw + in_off);
  ushort4 x2 = *(const ushort4*)(QKVraw + in_off + 64);
  float4 csA = *(const float4*)(&tab[t * 64 + d4]);      // c0 s0 c1 s1
  float4 csB = *(const float4*)(&tab[t * 64 + d4 + 2]);  // c2 s2 c3 s3
  ushort4 o1, o2;
  o1.x = f2b((b2f(x1.x) * csA.x - b2f(x2.x) * csA.y) * QSCALE);
  o2.x = f2b((b2f(x1.x) * csA.y + b2f(x2.x) * csA.x) * QSCALE);
  o1.y = f2b((b2f(x1.y) * csA.z - b2f(x2.y) * csA.w) * QSCALE);
  o2.y = f2b((b2f(x1.y) * csA.w + b2f(x2.y) * csA.z) * QSCALE);
  o1.z = f2b((b2f(x1.z) * csB.x - b2f(x2.z) * csB.y) * QSCALE);
  o2.z = f2b((b2f(x1.z) * csB.y + b2f(x2.z) * csB.x) * QSCALE);
  o1.w = f2b((b2f(x1.w) * csB.z - b2f(x2.w) * csB.w) * QSCALE);
  o2.w = f2b((b2f(x1.w) * csB.w + b2f(x2.w) * csB.z) * QSCALE);
  size_t out_off = ((size_t)(b * 16 + h) * 2048 + t) * 128 + d4;
  *(ushort4*)(Qb + out_off) = o1;
  *(ushort4*)(Qb + out_off + 64) = o2;
}

// QKVraw cols 2048..2559 = k -> rope -> Kb [(b*4+kh)*T + t][d], vectorized x4
__global__ void rope_k_k(const ushort_t* __restrict__ QKVraw, const float2* __restrict__ tab,
                         ushort_t* __restrict__ Kb) {
  int idx = blockIdx.x * blockDim.x + threadIdx.x;  // B*T*KH*16 = 262144
  int d4 = (idx & 15) * 4;
  int kh = (idx >> 4) & 3;
  int t = (idx >> 6) & 2047;
  int b = idx >> 17;
  size_t in_off = (size_t)(b * 2048 + t) * 3072 + 2048 + kh * 128 + d4;
  ushort4 x1 = *(const ushort4*)(QKVraw + in_off);
  ushort4 x2 = *(const ushort4*)(QKVraw + in_off + 64);
  float4 csA = *(const float4*)(&tab[t * 64 + d4]);
  float4 csB = *(const float4*)(&tab[t * 64 + d4 + 2]);
  ushort4 o1, o2;
  o1.x = f2b(b2f(x1.x) * csA.x - b2f(x2.x) * csA.y);
  o2.x = f2b(b2f(x1.x) * csA.y + b2f(x2.x) * csA.x);
  o1.y = f2b(b2f(x1.y) * csA.z - b2f(x2.y) * csA.w);
  o2.y = f2b(b2f(x1.y) * csA.w + b2f(x2.y) * csA.z);
  o1.z = f2b(b2f(x1.z) * csB.x - b2f(x2.z) * csB.y);
  o2.z = f2b(b2f(x1.z) * csB.y + b2f(x2.z) * csB.x);
  o1.w = f2b(b2f(x1.w) * csB.z - b2f(x2.w) * csB.w);
  o2.w = f2b(b2f(x1.w) * csB.w + b2f(x2.w) * csB.z);
  size_t out_off = ((size_t)(b * 4 + kh) * 2048 + t) * 128 + d4;
  *(ushort4*)(Kb + out_off) = o1;
  *(ushort4*)(Kb + out_off + 64) = o2;
}

// V fragment pre-pack: Vf short8 index = (((z*32+tile)*2+hv)*8+n)*64 + lane
// element j = V[b][t = tile*64 + kl][kh][d = n*16 + (lane&15)]
// kl = (hv*2 + ((j>>1)>>1))*16 + (lane>>4)*4 + 2*((j>>1)&1) + (j&1)
__global__ void v_frag_k(const ushort_t* __restrict__ QKVraw, ushort_t* __restrict__ Vf) {
  int idx = blockIdx.x * blockDim.x + threadIdx.x;  // 262144 short8 units
  int lane = idx & 63;
  int n = (idx >> 6) & 7;
  int hv = (idx >> 9) & 1;
  int tile = (idx >> 10) & 31;
  int z = idx >> 15;  // b*4+kh
  int b = z >> 2, kh = z & 3;
  int lr = lane & 15, lc = lane >> 4;
  int d = n * 16 + lr;
  union { ushort_t u[8]; short8 v; } out;
#pragma unroll
  for (int j = 0; j < 8; j++) {
    int tw = j >> 1, par = j & 1;
    int kl = (hv * 2 + (tw >> 1)) * 16 + lc * 4 + 2 * (tw & 1) + par;
    int t = tile * 64 + kl;
    out.u[j] = QKVraw[(size_t)(b * 2048 + t) * 3072 + 2560 + kh * 128 + d];
  }
  *(short8*)(Vf + (size_t)idx * 8) = out.v;
}

__device__ __forceinline__ void store_out(float* C, size_t idx, float v) { C[idx] = v; }
__device__ __forceinline__ void store_out(ushort_t* C, size_t idx, float v) { C[idx] = f2b(v); }

// ---------------- GEMM 256xBN 8-phase: counted vmcnt, m201 order, 100% CU fill ----
// NF = per-wave 16-col fragments (3 -> BN=192 QKV, 2 -> BN=128 proj).
// BM=256, BK=64 as k0/k1 halves. 512 thr = 8 waves (2M x 4N).
// Per-thread loads per STAGE: A-half = 2; B-half = NB (2 for NF=3 incl. the
// dummy for tid>=256 that keeps waves uniform; 1 for NF=2 -- B is exactly 512
// units, NO dummy). Counted-vmcnt constant VM = 2 + NB halves in flight after
// each publish (T4 formula): VM=4 for NF=3 (proven R12/R13), VM=3 for NF=2
// (re-derived: P1-end outstanding = t+1.A_k0(2)+B_k0(1); P3-end = A_k1(2)+
// B_k1(1); prologue 6 loads -> vmcnt(3) publishes A_k0/B_k0; tail vmcnt(0)).
// Phase = { ds_read subtile ; STAGE one t+1 half ; barrier ; lgkmcnt(0) ;
// setprio(1) MFMA setprio(0) ; [vmcnt(VM) at P1/P3] ; barrier }.
// Swizzle: chunk = lc ^ ((row>>1)&3), source pre-swizzled (both-sides).
// Grid: 1D 256 blocks (=1/CU), XCD-bijective swizzle (256 % 8 == 0).
template <int NF, typename OUT_T>
__global__ __launch_bounds__(512, 1) void gemm256(const ushort_t* __restrict__ A,
                                                  const ushort_t* __restrict__ Bt,
                                                  OUT_T* __restrict__ C,
                                                  int M, int N, int K) {
  __shared__ __attribute__((aligned(16))) ushort_t As[2][2][8192];
  __shared__ __attribute__((aligned(16))) ushort_t Bs[2][2][NF * 2048];
  __shared__ __attribute__((aligned(16))) ushort_t Scr[512];
  constexpr bool BTWO = (NF * 256 > 512);   // B-half needs a second load slot
  const int tid = threadIdx.x;
  const int lane = tid & 63;
  const int w = tid >> 6;          // 0..7
  const int lr = lane & 15, lc = lane >> 4;
  const int wm = w >> 2, wn = w & 3;
  // XCD-aware bijective swizzle over 1D grid
  const int nwg = gridDim.x;
  const int cpx = nwg >> 3;
  const int swz = (blockIdx.x & 7) * cpx + (blockIdx.x >> 3);
  const int bnc = N / (NF * 64);
  const int bm = swz / bnc, bn = swz % bnc;
  const ushort_t* Ab = A + (size_t)bm * 256 * K;
  const ushort_t* Bb = Bt + (size_t)bn * (NF * 64) * K;

  f32x4 acc[8][NF];
#pragma unroll
  for (int i = 0; i < 8; i++)
#pragma unroll
    for (int j = 0; j < NF; j++) acc[i][j] = (f32x4)(0.0f);

  auto STAGE = [&](int kt, int hid) {
    const int buf = kt & 1;
    const int kk = hid >> 1;
    const int kbase = kt * 64 + kk * 32;
    if (!(hid & 1)) {
      // A half: 1024 units; u0 = tid, u1 = 512 + tid
      ushort_t* db = &As[buf][kk][0];
      {
        const int u = tid, row = u >> 2, c = u & 3;
        const int lch = c ^ ((row >> 1) & 3);
        async16(Ab + (size_t)row * K + kbase + lch * 8, db + u * 8);
      }
      {
        const int u = 512 + tid, row = u >> 2, c = u & 3;
        const int lch = c ^ ((row >> 1) & 3);
        async16(Ab + (size_t)row * K + kbase + lch * 8, db + u * 8);
      }
    } else {
      // B half: NF*256 units; load0 = all threads
      ushort_t* db = &Bs[buf][kk][0];
      {
        const int u = tid, row = u >> 2, c = u & 3;
        const int lch = c ^ ((row >> 1) & 3);
        async16(Bb + (size_t)row * K + kbase + lch * 8, db + u * 8);
      }
      if constexpr (BTWO) {
        if (tid < NF * 256 - 512) {
          const int u = 512 + tid, row = u >> 2, c = u & 3;
          const int lch = c ^ ((row >> 1) & 3);
          async16(Bb + (size_t)row * K + kbase + lch * 8, db + u * 8);
        } else {
          // dummy keeps per-wave vmcnt counts uniform; Scr never read
          async16(Bb + (size_t)(tid & 255) * 8, &Scr[0]);
        }
      }
      // NF==2: B is exactly 512 units -> uniform 1 load/thread, no dummy
    }
  };

#define VMCNT_PUB() do {                                   \
    if constexpr (BTWO) {                                  \
      asm volatile("s_waitcnt vmcnt(4)" ::: "memory");     \
    } else {                                               \
      asm volatile("s_waitcnt vmcnt(3)" ::: "memory");     \
    }                                                      \
  } while (0)

  const int nt = K >> 6;
  // prologue: stage tile0 fully; publish A_k0/B_k0 (keep A_k1/B_k1 in flight)
  STAGE(0, 0); STAGE(0, 1); STAGE(0, 2); STAGE(0, 3);
  VMCNT_PUB();
  __builtin_amdgcn_s_barrier();

#pragma unroll 1
  for (int t = 0; t < nt; ++t) {
    const int buf = t & 1;
    const ushort_t* Ak0 = &As[buf][0][0];
    const ushort_t* Ak1 = &As[buf][1][0];
    const ushort_t* Bk0 = &Bs[buf][0][0];
    const ushort_t* Bk1 = &Bs[buf][1][0];
    short8 af[4], bf[NF];

    // ---- P0: ds B_k0 + A[mq0,k0]; stage t+1.A_k0
#pragma unroll
    for (int nf = 0; nf < NF; nf++) {
      const int row = wn * (NF * 16) + nf * 16 + lr;
      bf[nf] = *(const short8*)(Bk0 + row * 32 + ((lc ^ ((row >> 1) & 3)) * 8));
    }
#pragma unroll
    for (int mf = 0; mf < 4; mf++) {
      const int row = wm * 128 + mf * 16 + lr;
      af[mf] = *(const short8*)(Ak0 + row * 32 + ((lc ^ ((row >> 1) & 3)) * 8));
    }
    if (t + 1 < nt) STAGE(t + 1, 0);
    __builtin_amdgcn_s_barrier();
    asm volatile("s_waitcnt lgkmcnt(0)" ::: "memory");
    __builtin_amdgcn_sched_barrier(0);
    __builtin_amdgcn_s_setprio(1);
#pragma unroll
    for (int mf = 0; mf < 4; mf++)
#pragma unroll
      for (int nf = 0; nf < NF; nf++)
        acc[mf][nf] = mfma16(af[mf], bf[nf], acc[mf][nf]);
    __builtin_amdgcn_s_setprio(0);
    __builtin_amdgcn_s_barrier();

    // ---- P1: ds A[mq1,k0]; stage t+1.B_k0; MFMA; vmcnt publishes A_k1/B_k1
#pragma unroll
    for (int mf = 0; mf < 4; mf++) {
      const int row = wm * 128 + 64 + mf * 16 + lr;
      af[mf] = *(const short8*)(Ak0 + row * 32 + ((lc ^ ((row >> 1) & 3)) * 8));
    }
    if (t + 1 < nt) STAGE(t + 1, 1);
    __builtin_amdgcn_s_barrier();
    asm volatile("s_waitcnt lgkmcnt(0)" ::: "memory");
    __builtin_amdgcn_sched_barrier(0);
    __builtin_amdgcn_s_setprio(1);
#pragma unroll
    for (int mf = 0; mf < 4; mf++)
#pragma unroll
      for (int nf = 0; nf < NF; nf++)
        acc[4 + mf][nf] = mfma16(af[mf], bf[nf], acc[4 + mf][nf]);
    __builtin_amdgcn_s_setprio(0);
    if (t + 1 < nt) {
      VMCNT_PUB();
    } else {
      asm volatile("s_waitcnt vmcnt(0)" ::: "memory");
    }
    __builtin_amdgcn_s_barrier();

    // ---- P2: ds B_k1 + A[mq0,k1]; stage t+1.A_k1; MFMA
#pragma unroll
    for (int nf = 0; nf < NF; nf++) {
      const int row = wn * (NF * 16) + nf * 16 + lr;
      bf[nf] = *(const short8*)(Bk1 + row * 32 + ((lc ^ ((row >> 1) & 3)) * 8));
    }
#pragma unroll
    for (int mf = 0; mf < 4; mf++) {
      const int row = wm * 128 + mf * 16 + lr;
      af[mf] = *(const short8*)(Ak1 + row * 32 + ((lc ^ ((row >> 1) & 3)) * 8));
    }
    if (t + 1 < nt) STAGE(t + 1, 2);
    __builtin_amdgcn_s_barrier();
    asm volatile("s_waitcnt lgkmcnt(0)" ::: "memory");
    __builtin_amdgcn_sched_barrier(0);
    __builtin_amdgcn_s_setprio(1);
#pragma unroll
    for (int mf = 0; mf < 4; mf++)
#pragma unroll
      for (int nf = 0; nf < NF; nf++)
        acc[mf][nf] = mfma16(af[mf], bf[nf], acc[mf][nf]);
    __builtin_amdgcn_s_setprio(0);
    __builtin_amdgcn_s_barrier();

    // ---- P3: ds A[mq1,k1]; stage t+1.B_k1; MFMA; vmcnt publishes t+1 A_k0/B_k0
#pragma unroll
    for (int mf = 0; mf < 4; mf++) {
      const int row = wm * 128 + 64 + mf * 16 + lr;
      af[mf] = *(const short8*)(Ak1 + row * 32 + ((lc ^ ((row >> 1) & 3)) * 8));
    }
    if (t + 1 < nt) STAGE(t + 1, 3);
    __builtin_amdgcn_s_barrier();
    asm volatile("s_waitcnt lgkmcnt(0)" ::: "memory");
    __builtin_amdgcn_sched_barrier(0);
    __builtin_amdgcn_s_setprio(1);
#pragma unroll
    for (int mf = 0; mf < 4; mf++)
#pragma unroll
      for (int nf = 0; nf < NF; nf++)
        acc[4 + mf][nf] = mfma16(af[mf], bf[nf], acc[4 + mf][nf]);
    __builtin_amdgcn_s_setprio(0);
    if (t + 1 < nt) {
      VMCNT_PUB();
    }
    __builtin_amdgcn_s_barrier();
  }
#undef VMCNT_PUB

#pragma unroll
  for (int mfp = 0; mfp < 8; mfp++) {
#pragma unroll
    for (int nf = 0; nf < NF; nf++) {
      const int row = bm * 256 + wm * 128 + mfp * 16 + lc * 4;
      const int col = bn * (NF * 64) + wn * (NF * 16) + nf * 16 + lr;
#pragma unroll
      for (int r = 0; r < 4; r++)
        store_out(C, (size_t)(row + r) * N + col, acc[mfp][nf][r]);
    }
  }
}

// ---------------- flash attention (causal GQA) — R9 config (best: 76us) ----------------
__global__ __launch_bounds__(256, 2) void attn_k(const ushort_t* __restrict__ Qb,
                                                 const ushort_t* __restrict__ Kb,
                                                 const ushort_t* __restrict__ Vf,
                                                 ushort_t* __restrict__ Yb) {
  __shared__ __attribute__((aligned(16))) ushort_t Ks[2][64 * 128];  // 32 KB
  const int tid = threadIdx.x;
  const int lane = tid & 63;
  const int w = tid >> 6;
  const int lr = lane & 15, lc = lane >> 4;
  const int gy = blockIdx.y;
  const int h = gy;
  const int b = blockIdx.z;
  const int kh = h >> 2;
  const int qc = b ? (15 - ((blockIdx.x + gy) & 15)) : ((blockIdx.x + gy) & 15);
  const int q0w = qc * 128 + w * 32;

  const ushort_t* Qp = Qb + (size_t)(b * 16 + h) * T_ * D_;
  const ushort_t* Kp = Kb + (size_t)(b * 4 + kh) * T_ * D_;
  const ushort_t* Vfb = Vf + (size_t)(b * 4 + kh) * 262144;

  const int st_row = tid >> 4;
  const int st_slot = tid & 15;

  short8 qf[2][4];
#pragma unroll
  for (int f = 0; f < 2; f++)
#pragma unroll
    for (int c = 0; c < 4; c++)
      qf[f][c] = *(const short8*)(Qp + (size_t)(q0w + f * 16 + lr) * D_ + c * 32 + lc * 8);

  f32x4 o[2][8];
#pragma unroll
  for (int f = 0; f < 2; f++)
#pragma unroll
    for (int n = 0; n < 8; n++) o[f][n] = (f32x4)(0.0f);
  float m[2] = {-1e30f, -1e30f}, l[2] = {0.0f, 0.0f};

  const int nt = 2 * qc + 2;

#pragma unroll
  for (int i = 0; i < 4; i++) {
    int row = i * 16 + st_row;
    async16(Kp + (size_t)row * D_ + (((st_slot - row) & 15) * 8),
            &Ks[0][0] + row * 128 + st_slot * 8);
  }

#pragma unroll 1
  for (int ti = 0; ti < nt; ti++) {
    __syncthreads();
    const int kv0 = ti * 64;
    if (ti + 1 < nt) {
      const ushort_t* Kn = Kp + (size_t)(kv0 + 64) * D_;
      ushort_t* dst = &Ks[(ti + 1) & 1][0];
#pragma unroll
      for (int i = 0; i < 4; i++) {
        int row = i * 16 + st_row;
        async16(Kn + (size_t)row * D_ + (((st_slot - row) & 15) * 8),
                dst + row * 128 + st_slot * 8);
      }
    }
    if (kv0 > q0w + 31) continue;
    const ushort_t* Kl = &Ks[ti & 1][0];
    const ushort_t* Vt0 = Vfb + (size_t)(ti * 2) * 4096;
    short8 vr0[8];
#pragma unroll
    for (int n = 0; n < 8; n++)
      vr0[n] = *(const short8*)(Vt0 + n * 512 + lane * 8);
    f32x4 s[2][4];
#pragma unroll
    for (int f = 0; f < 2; f++)
#pragma unroll
      for (int kj = 0; kj < 4; kj++) s[f][kj] = (f32x4)(0.0f);
    __builtin_amdgcn_s_setprio(1);
#pragma unroll
    for (int c = 0; c < 4; c++) {
      short8 kf[4];
#pragma unroll
      for (int kj = 0; kj < 4; kj++)
        kf[kj] = *(const short8*)(Kl + (kj * 16 + lr) * 128 + (((c * 4 + lc + lr) & 15) * 8));
#pragma unroll
      for (int f = 0; f < 2; f++)
#pragma unroll
        for (int kj = 0; kj < 4; kj++)
          s[f][kj] = mfma16(kf[kj], qf[f][c], s[f][kj]);
    }
    __builtin_amdgcn_s_setprio(0);
    const ushort_t* Vt1 = Vfb + (size_t)(ti * 2 + 1) * 4096;
    short8 vr1[8];
#pragma unroll
    for (int n = 0; n < 8; n++)
      vr1[n] = *(const short8*)(Vt1 + n * 512 + lane * 8);
    const bool maskt = (kv0 + 63 > q0w);
    union { unsigned u[4]; short8 v; } pa0[2], pa1[2];
#pragma unroll
    for (int f = 0; f < 2; f++) {
      const int q = q0w + f * 16 + lr;
      float pv[16];
      float mx = -1e30f;
      if (maskt) {
#pragma unroll
        for (int kj = 0; kj < 4; kj++)
#pragma unroll
          for (int r = 0; r < 4; r++) {
            float a = s[f][kj][r];
            if (kv0 + kj * 16 + lc * 4 + r > q) a = -1e30f;
            pv[kj * 4 + r] = a;
            mx = fmaxf(mx, a);
          }
      } else {
#pragma unroll
        for (int kj = 0; kj < 4; kj++)
#pragma unroll
          for (int r = 0; r < 4; r++) {
            float a = s[f][kj][r];
            pv[kj * 4 + r] = a;
            mx = fmaxf(mx, a);
          }
      }
      mx = fmaxf(mx, __shfl_xor(mx, 16));
      mx = fmaxf(mx, __shfl_xor(mx, 32));
      const bool need = __any(mx > m[f] + 8.0f);
      const float mn = need ? fmaxf(m[f], mx) : m[f];
      float rs = 0.0f;
#pragma unroll
      for (int i = 0; i < 16; i++) {
        pv[i] = exp2f(pv[i] - mn);
        rs += pv[i];
      }
      rs += __shfl_xor(rs, 16);
      rs += __shfl_xor(rs, 32);
#pragma unroll
      for (int kj = 0; kj < 2; kj++) {
        pa0[f].u[kj * 2] = cvtpk(pv[kj * 4], pv[kj * 4 + 1]);
        pa0[f].u[kj * 2 + 1] = cvtpk(pv[kj * 4 + 2], pv[kj * 4 + 3]);
        pa1[f].u[kj * 2] = cvtpk(pv[8 + kj * 4], pv[8 + kj * 4 + 1]);
        pa1[f].u[kj * 2 + 1] = cvtpk(pv[8 + kj * 4 + 2], pv[8 + kj * 4 + 3]);
      }
      if (need) {
        float al = exp2f(m[f] - mn);
        m[f] = mn;
        l[f] = l[f] * al + rs;
        float alT[4];
#pragma unroll
        for (int r = 0; r < 4; r++)
          alT[r] = __shfl(al, (lane & 48) | (lc * 4 + r));
#pragma unroll
        for (int n = 0; n < 8; n++)
#pragma unroll
          for (int r = 0; r < 4; r++) o[f][n][r] *= alT[r];
      } else {
        l[f] += rs;
      }
    }
    __builtin_amdgcn_s_setprio(1);
#pragma unroll
    for (int n = 0; n < 8; n++) {
      o[0][n] = mfma16(pa0[0].v, vr0[n], o[0][n]);
      o[1][n] = mfma16(pa0[1].v, vr0[n], o[1][n]);
    }
#pragma unroll
    for (int n = 0; n < 8; n++) {
      o[0][n] = mfma16(pa1[0].v, vr1[n], o[0][n]);
      o[1][n] = mfma16(pa1[1].v, vr1[n], o[1][n]);
    }
    __builtin_amdgcn_s_setprio(0);
  }
#pragma unroll
  for (int f = 0; f < 2; f++) {
    float inv = 1.0f / l[f];
    float invT[4];
#pragma unroll
    for (int r = 0; r < 4; r++)
      invT[r] = __shfl(inv, (lane & 48) | (lc * 4 + r));
#pragma unroll
    for (int n = 0; n < 8; n++)
#pragma unroll
      for (int r = 0; r < 4; r++) {
        int qo = q0w + f * 16 + lc * 4 + r;
        int d = n * 16 + lr;
        Yb[(size_t)(b * T_ + qo) * 2048 + h * 128 + d] = f2b(o[f][n][r] * invT[r]);
      }
  }
}

// ---------------- launch ----------------

extern "C" void kernel_launch(void* const* d_in, const int* in_sizes, int n_in,
                              void* d_out, int out_size, void* d_ws, size_t ws_size,
                              hipStream_t stream) {
  (void)in_sizes; (void)n_in; (void)out_size; (void)ws_size;
  const float* x = (const float*)d_in[0];
  const float* wq = (const float*)d_in[1];
  const float* wkv = (const float*)d_in[2];
  const float* wproj = (const float*)d_in[3];
  const float* omega = (const float*)d_in[4];
  float* out = (float*)d_out;
  char* ws = (char*)d_ws;

  ushort_t* xb     = (ushort_t*)(ws + 0);          // 4096x2048 bf16 = 16.8MB
  ushort_t* wqkvT  = (ushort_t*)(ws + 16777216);   // [3072][2048] bf16 (wqT then wkvT)
  ushort_t* wkvT   = (ushort_t*)(ws + 25165824);   // tail of wqkvT
  ushort_t* wprojT = (ushort_t*)(ws + 29360128);   // 2048x2048 bf16
  ushort_t* QKVraw = (ushort_t*)(ws + 37748736);   // 4096x3072 bf16 = 25.2MB
  ushort_t* Qb     = (ushort_t*)(ws + 62914560);   // [b][h][t][d] bf16
  ushort_t* Kb     = (ushort_t*)(ws + 79691776);   // [b][kh][t][d] bf16
  ushort_t* Vf     = (ushort_t*)(ws + 83886080);   // V fragment-packed, 4MB
  ushort_t* Yb     = (ushort_t*)(ws + 88080384);   // 4096x2048 bf16
  float2*   tab    = (float2*)(ws + 104857600);    // 2048x64 float2 = 1MB

  convert_f32_bf16<<<8192, 256, 0, stream>>>(x, xb, 2097152);
  transpose_to_bf16<<<dim3(64, 64), dim3(32, 8), 0, stream>>>(wq, wqkvT, 2048, 2048);
  transpose_to_bf16<<<dim3(32, 64), dim3(32, 8), 0, stream>>>(wkv, wkvT, 2048, 1024);
  transpose_to_bf16<<<dim3(64, 64), dim3(32, 8), 0, stream>>>(wproj, wprojT, 2048, 2048);
  rope_tab_k<<<512, 256, 0, stream>>>(omega, tab);

  // merged QKV projection via 256x192 8-phase (256 blocks = 100% CU fill)
  gemm256<3><<<256, 512, 0, stream>>>(xb, wqkvT, QKVraw, 4096, 3072, 2048);

  rope_q_k<<<4096, 256, 0, stream>>>(QKVraw, tab, Qb);
  rope_k_k<<<1024, 256, 0, stream>>>(QKVraw, tab, Kb);
  v_frag_k<<<1024, 256, 0, stream>>>(QKVraw, Vf);

  attn_k<<<dim3(16, 16, 2), 256, 0, stream>>>(Qb, Kb, Vf, Yb);

  // output projection via 256x128 8-phase (256 blocks = 100% CU fill, VM=3)
  gemm256<2><<<256, 512, 0, stream>>>(Yb, wprojT, out, 4096, 2048, 2048);
}

// Round 16
// 213.981 us; speedup vs baseline: 1.0313x; 1.0289x over previous
//
#include <hip/hip_runtime.h>
#include <hip/hip_bf16.h>

#define B_ 2
#define T_ 2048
#define C_ 2048
#define H_ 16
#define KH_ 4
#define D_ 128

typedef unsigned short ushort_t;
typedef __attribute__((ext_vector_type(8))) short short8;
typedef __attribute__((ext_vector_type(4))) float f32x4;

#define RSQRT_D 0.08838834764831845f
#define L2E 1.4426950408889634f
// Q pre-scale: 1/sqrt(D) * log2(e)  ->  QK^T lands in log2 units, softmax is pure exp2
#define QSCALE (0.08838834764831845f * 1.4426950408889634f)

__device__ __forceinline__ ushort_t f2b(float f) {
  union { float f; unsigned u; } v; v.f = f;
  unsigned r = v.u + 0x7fffu + ((v.u >> 16) & 1u);
  return (ushort_t)(r >> 16);
}
__device__ __forceinline__ float b2f(ushort_t u) {
  union { unsigned u; float f; } v; v.u = ((unsigned)u) << 16;
  return v.f;
}

__device__ __forceinline__ f32x4 mfma16(short8 a, short8 b, f32x4 c) {
  return __builtin_amdgcn_mfma_f32_16x16x32_bf16(a, b, c, 0, 0, 0);
}

__device__ __forceinline__ void async16(const void* g, void* l) {
  __builtin_amdgcn_global_load_lds(
      (const __attribute__((address_space(1))) void*)g,
      (__attribute__((address_space(3))) void*)l, 16, 0, 0);
}

// packed f32x2 -> bf16x2 (RTNE); dst.lo = bf16(lo), dst.hi = bf16(hi)
__device__ __forceinline__ unsigned cvtpk(float lo, float hi) {
  unsigned r;
  asm volatile("v_cvt_pk_bf16_f32 %0, %1, %2" : "=v"(r) : "v"(lo), "v"(hi));
  return r;
}

// ---------------- small prep kernels ----------------

__global__ void convert_f32_bf16(const float* __restrict__ in, ushort_t* __restrict__ out, int n4) {
  int i = blockIdx.x * blockDim.x + threadIdx.x;
  if (i >= n4) return;
  float4 v = ((const float4*)in)[i];
  ushort4 o;
  o.x = f2b(v.x); o.y = f2b(v.y); o.z = f2b(v.z); o.w = f2b(v.w);
  ((ushort4*)out)[i] = o;
}

// fused weight transpose: z=0 wq(2048x2048)->wqkvT, z=1 wkv(2048x1024)->wqkvT+2048*2048,
// z=2 wproj(2048x2048)->wprojT.  out[c][r] = bf16(in[r][c])
__global__ void transpose_w3(const float* __restrict__ wq, const float* __restrict__ wkv,
                             const float* __restrict__ wproj, ushort_t* __restrict__ wqkvT,
                             ushort_t* __restrict__ wprojT) {
  __shared__ float tile[32][33];
  const int z = blockIdx.z;
  const float* in = (z == 0) ? wq : (z == 1) ? wkv : wproj;
  ushort_t* out = (z == 0) ? wqkvT : (z == 1) ? (wqkvT + 2048 * 2048) : wprojT;
  const int Cc = (z == 1) ? 1024 : 2048;   // source cols
  const int Rr = 2048;                     // source rows
  int c0 = blockIdx.x * 32, r0 = blockIdx.y * 32;
  if (c0 >= Cc) return;
  int tx = threadIdx.x, ty = threadIdx.y;
#pragma unroll
  for (int i = 0; i < 4; i++) {
    int r = ty + i * 8;
    tile[r][tx] = in[(size_t)(r0 + r) * Cc + c0 + tx];
  }
  __syncthreads();
#pragma unroll
  for (int i = 0; i < 4; i++) {
    int r = ty + i * 8;
    out[(size_t)(c0 + r) * Rr + r0 + tx] = f2b(tile[tx][r]);
  }
}

// cos/sin table: tab[t*64+d] = (cos(t*omega[d]), sin(t*omega[d]))
__global__ void rope_tab_k(const float* __restrict__ omega, float2* __restrict__ tab) {
  int idx = blockIdx.x * blockDim.x + threadIdx.x;  // 2048*64
  int d = idx & 63;
  int t = idx >> 6;
  float ang = (float)t * omega[d];
  tab[idx] = make_float2(cosf(ang), sinf(ang));
}

// QKVraw [b*T+t][3072]: cols 0..2047 = q -> rope (pre-scaled by QSCALE)
__global__ void rope_q_k(const ushort_t* __restrict__ QKVraw, const float2* __restrict__ tab,
                         ushort_t* __restrict__ Qb) {
  int idx = blockIdx.x * blockDim.x + threadIdx.x;  // B*T*H*16 = 1048576
  int d4 = (idx & 15) * 4;
  int h = (idx >> 4) & 15;
  int t = (idx >> 8) & 2047;
  int b = idx >> 19;
  size_t in_off = (size_t)(b * 2048 + t) * 3072 + h * 128 + d4;
  ushort4 x1 = *(const ushort4*)(QKVraw + in_off);
  ushort4 x2 = *(const ushort4*)(QKVraw + in_off + 64);
  float4 csA = *(const float4*)(&tab[t * 64 + d4]);      // c0 s0 c1 s1
  float4 csB = *(const float4*)(&tab[t * 64 + d4 + 2]);  // c2 s2 c3 s3
  ushort4 o1, o2;
  o1.x = f2b((b2f(x1.x) * csA.x - b2f(x2.x) * csA.y) * QSCALE);
  o2.x = f2b((b2f(x1.x) * csA.y + b2f(x2.x) * csA.x) * QSCALE);
  o1.y = f2b((b2f(x1.y) * csA.z - b2f(x2.y) * csA.w) * QSCALE);
  o2.y = f2b((b2f(x1.y) * csA.w + b2f(x2.y) * csA.z) * QSCALE);
  o1.z = f2b((b2f(x1.z) * csB.x - b2f(x2.z) * csB.y) * QSCALE);
  o2.z = f2b((b2f(x1.z) * csB.y + b2f(x2.z) * csB.x) * QSCALE);
  o1.w = f2b((b2f(x1.w) * csB.z - b2f(x2.w) * csB.w) * QSCALE);
  o2.w = f2b((b2f(x1.w) * csB.w + b2f(x2.w) * csB.z) * QSCALE);
  size_t out_off = ((size_t)(b * 16 + h) * 2048 + t) * 128 + d4;
  *(ushort4*)(Qb + out_off) = o1;
  *(ushort4*)(Qb + out_off + 64) = o2;
}

// QKVraw cols 2048..2559 = k -> rope -> Kb [(b*4+kh)*T + t][d], vectorized x4
__global__ void rope_k_k(const ushort_t* __restrict__ QKVraw, const float2* __restrict__ tab,
                         ushort_t* __restrict__ Kb) {
  int idx = blockIdx.x * blockDim.x + threadIdx.x;  // B*T*KH*16 = 262144
  int d4 = (idx & 15) * 4;
  int kh = (idx >> 4) & 3;
  int t = (idx >> 6) & 2047;
  int b = idx >> 17;
  size_t in_off = (size_t)(b * 2048 + t) * 3072 + 2048 + kh * 128 + d4;
  ushort4 x1 = *(const ushort4*)(QKVraw + in_off);
  ushort4 x2 = *(const ushort4*)(QKVraw + in_off + 64);
  float4 csA = *(const float4*)(&tab[t * 64 + d4]);
  float4 csB = *(const float4*)(&tab[t * 64 + d4 + 2]);
  ushort4 o1, o2;
  o1.x = f2b(b2f(x1.x) * csA.x - b2f(x2.x) * csA.y);
  o2.x = f2b(b2f(x1.x) * csA.y + b2f(x2.x) * csA.x);
  o1.y = f2b(b2f(x1.y) * csA.z - b2f(x2.y) * csA.w);
  o2.y = f2b(b2f(x1.y) * csA.w + b2f(x2.y) * csA.z);
  o1.z = f2b(b2f(x1.z) * csB.x - b2f(x2.z) * csB.y);
  o2.z = f2b(b2f(x1.z) * csB.y + b2f(x2.z) * csB.x);
  o1.w = f2b(b2f(x1.w) * csB.z - b2f(x2.w) * csB.w);
  o2.w = f2b(b2f(x1.w) * csB.w + b2f(x2.w) * csB.z);
  size_t out_off = ((size_t)(b * 4 + kh) * 2048 + t) * 128 + d4;
  *(ushort4*)(Kb + out_off) = o1;
  *(ushort4*)(Kb + out_off + 64) = o2;
}

// V fragment pre-pack: Vf short8 index = (((z*32+tile)*2+hv)*8+n)*64 + lane
// element j = V[b][t = tile*64 + kl][kh][d = n*16 + (lane&15)]
// kl = (hv*2 + ((j>>1)>>1))*16 + (lane>>4)*4 + 2*((j>>1)&1) + (j&1)
__global__ void v_frag_k(const ushort_t* __restrict__ QKVraw, ushort_t* __restrict__ Vf) {
  int idx = blockIdx.x * blockDim.x + threadIdx.x;  // 262144 short8 units
  int lane = idx & 63;
  int n = (idx >> 6) & 7;
  int hv = (idx >> 9) & 1;
  int tile = (idx >> 10) & 31;
  int z = idx >> 15;  // b*4+kh
  int b = z >> 2, kh = z & 3;
  int lr = lane & 15, lc = lane >> 4;
  int d = n * 16 + lr;
  union { ushort_t u[8]; short8 v; } out;
#pragma unroll
  for (int j = 0; j < 8; j++) {
    int tw = j >> 1, par = j & 1;
    int kl = (hv * 2 + (tw >> 1)) * 16 + lc * 4 + 2 * (tw & 1) + par;
    int t = tile * 64 + kl;
    out.u[j] = QKVraw[(size_t)(b * 2048 + t) * 3072 + 2560 + kh * 128 + d];
  }
  *(short8*)(Vf + (size_t)idx * 8) = out.v;
}

__device__ __forceinline__ void store_out(float* C, size_t idx, float v) { C[idx] = v; }
__device__ __forceinline__ void store_out(ushort_t* C, size_t idx, float v) { C[idx] = f2b(v); }

// ---------------- GEMM 128x128 (proj): 2-phase dbuf, counted vmcnt (best for this shape) ---

template <typename OUT_T>
__global__ __launch_bounds__(256) void gemm_bt(const ushort_t* __restrict__ A,
                                               const ushort_t* __restrict__ Bt,
                                               OUT_T* __restrict__ C,
                                               int M, int N, int K) {
  __shared__ __attribute__((aligned(16))) ushort_t As[2][128 * 32];
  __shared__ __attribute__((aligned(16))) ushort_t Bs[2][128 * 32];
  const int tid = threadIdx.x;
  const int lane = tid & 63;
  const int w = tid >> 6;
  const int bm = blockIdx.y, bn = blockIdx.x;
  const int lr = lane & 15, lc = lane >> 4;
  const int wr = (w >> 1) * 64, wc = (w & 1) * 64;
  const ushort_t* Ab = A + (size_t)bm * 128 * K;
  const ushort_t* Bb = Bt + (size_t)bn * 128 * K;
  const int srow = tid >> 2;
  const int scol = (tid & 3) * 8;
  f32x4 acc[4][4];
#pragma unroll
  for (int i = 0; i < 4; i++)
#pragma unroll
    for (int j = 0; j < 4; j++) acc[i][j] = (f32x4)(0.0f);

  async16(Ab + (size_t)srow * K + scol, &As[0][0] + srow * 32 + scol);
  async16(Ab + (size_t)(srow + 64) * K + scol, &As[0][0] + (srow + 64) * 32 + scol);
  async16(Bb + (size_t)srow * K + scol, &Bs[0][0] + srow * 32 + scol);
  async16(Bb + (size_t)(srow + 64) * K + scol, &Bs[0][0] + (srow + 64) * 32 + scol);

  const int nt = K >> 5;
#pragma unroll 2
  for (int t = 0; t < nt - 1; t++) {
    const int cur = t & 1;
    {
      const int k1 = (t + 1) << 5;
      ushort_t* Ad = &As[cur ^ 1][0];
      ushort_t* Bd = &Bs[cur ^ 1][0];
      async16(Ab + (size_t)srow * K + k1 + scol, Ad + srow * 32 + scol);
      async16(Ab + (size_t)(srow + 64) * K + k1 + scol, Ad + (srow + 64) * 32 + scol);
      async16(Bb + (size_t)srow * K + k1 + scol, Bd + srow * 32 + scol);
      async16(Bb + (size_t)(srow + 64) * K + k1 + scol, Bd + (srow + 64) * 32 + scol);
    }
    asm volatile("s_waitcnt vmcnt(4)" ::: "memory");
    __builtin_amdgcn_s_barrier();
    __builtin_amdgcn_sched_barrier(0);
    const ushort_t* Al = &As[cur][0];
    const ushort_t* Bl = &Bs[cur][0];
    short8 af[4], bf[4];
#pragma unroll
    for (int mi = 0; mi < 4; mi++)
      af[mi] = *(const short8*)(Al + (wr + mi * 16 + lr) * 32 + lc * 8);
#pragma unroll
    for (int ni = 0; ni < 4; ni++)
      bf[ni] = *(const short8*)(Bl + (wc + ni * 16 + lr) * 32 + lc * 8);
#pragma unroll
    for (int mi = 0; mi < 4; mi++)
#pragma unroll
      for (int ni = 0; ni < 4; ni++)
        acc[mi][ni] = mfma16(af[mi], bf[ni], acc[mi][ni]);
    asm volatile("" ::: "memory");
    __builtin_amdgcn_s_barrier();
    asm volatile("" ::: "memory");
  }
  {
    const int cur = (nt - 1) & 1;
    asm volatile("s_waitcnt vmcnt(0)" ::: "memory");
    __builtin_amdgcn_s_barrier();
    __builtin_amdgcn_sched_barrier(0);
    const ushort_t* Al = &As[cur][0];
    const ushort_t* Bl = &Bs[cur][0];
    short8 af[4], bf[4];
#pragma unroll
    for (int mi = 0; mi < 4; mi++)
      af[mi] = *(const short8*)(Al + (wr + mi * 16 + lr) * 32 + lc * 8);
#pragma unroll
    for (int ni = 0; ni < 4; ni++)
      bf[ni] = *(const short8*)(Bl + (wc + ni * 16 + lr) * 32 + lc * 8);
#pragma unroll
    for (int mi = 0; mi < 4; mi++)
#pragma unroll
      for (int ni = 0; ni < 4; ni++)
        acc[mi][ni] = mfma16(af[mi], bf[ni], acc[mi][ni]);
  }
#pragma unroll
  for (int mi = 0; mi < 4; mi++) {
#pragma unroll
    for (int ni = 0; ni < 4; ni++) {
      int row = bm * 128 + wr + mi * 16 + lc * 4;
      int col = bn * 128 + wc + ni * 16 + lr;
#pragma unroll
      for (int r = 0; r < 4; r++)
        store_out(C, (size_t)(row + r) * N + col, acc[mi][ni][r]);
    }
  }
}

// ---------------- GEMM 256x192 8-phase (QKV): counted vmcnt(4), 100% CU fill ----
// Best-measured structure for the QKV shape (12 MFMA/phase; NF=2 variant was
// slower than 2-phase for proj -- 8 MFMA/phase doesn't amortize phase overhead).
__global__ __launch_bounds__(512, 1) void gemm256q(const ushort_t* __restrict__ A,
                                                   const ushort_t* __restrict__ Bt,
                                                   ushort_t* __restrict__ C,
                                                   int M, int N, int K) {
  __shared__ __attribute__((aligned(16))) ushort_t As[2][2][8192];
  __shared__ __attribute__((aligned(16))) ushort_t Bs[2][2][6144];
  __shared__ __attribute__((aligned(16))) ushort_t Scr[512];
  const int tid = threadIdx.x;
  const int lane = tid & 63;
  const int w = tid >> 6;          // 0..7
  const int lr = lane & 15, lc = lane >> 4;
  const int wm = w >> 2, wn = w & 3;
  const int nwg = gridDim.x;
  const int cpx = nwg >> 3;
  const int swz = (blockIdx.x & 7) * cpx + (blockIdx.x >> 3);
  const int bnc = N / 192;
  const int bm = swz / bnc, bn = swz % bnc;
  const ushort_t* Ab = A + (size_t)bm * 256 * K;
  const ushort_t* Bb = Bt + (size_t)bn * 192 * K;

  f32x4 acc[8][3];
#pragma unroll
  for (int i = 0; i < 8; i++)
#pragma unroll
    for (int j = 0; j < 3; j++) acc[i][j] = (f32x4)(0.0f);

  auto STAGE = [&](int kt, int hid) {
    const int buf = kt & 1;
    const int kk = hid >> 1;
    const int kbase = kt * 64 + kk * 32;
    if (!(hid & 1)) {
      ushort_t* db = &As[buf][kk][0];
      {
        const int u = tid, row = u >> 2, c = u & 3;
        const int lch = c ^ ((row >> 1) & 3);
        async16(Ab + (size_t)row * K + kbase + lch * 8, db + u * 8);
      }
      {
        const int u = 512 + tid, row = u >> 2, c = u & 3;
        const int lch = c ^ ((row >> 1) & 3);
        async16(Ab + (size_t)row * K + kbase + lch * 8, db + u * 8);
      }
    } else {
      ushort_t* db = &Bs[buf][kk][0];
      {
        const int u = tid, row = u >> 2, c = u & 3;
        const int lch = c ^ ((row >> 1) & 3);
        async16(Bb + (size_t)row * K + kbase + lch * 8, db + u * 8);
      }
      if (tid < 256) {
        const int u = 512 + tid, row = u >> 2, c = u & 3;
        const int lch = c ^ ((row >> 1) & 3);
        async16(Bb + (size_t)row * K + kbase + lch * 8, db + u * 8);
      } else {
        async16(Bb + (size_t)(tid & 255) * 8, &Scr[0]);
      }
    }
  };

  const int nt = K >> 6;
  STAGE(0, 0); STAGE(0, 1); STAGE(0, 2); STAGE(0, 3);
  asm volatile("s_waitcnt vmcnt(4)" ::: "memory");
  __builtin_amdgcn_s_barrier();

#pragma unroll 1
  for (int t = 0; t < nt; ++t) {
    const int buf = t & 1;
    const ushort_t* Ak0 = &As[buf][0][0];
    const ushort_t* Ak1 = &As[buf][1][0];
    const ushort_t* Bk0 = &Bs[buf][0][0];
    const ushort_t* Bk1 = &Bs[buf][1][0];
    short8 af[4], bf[3];

    // ---- P0
#pragma unroll
    for (int nf = 0; nf < 3; nf++) {
      const int row = wn * 48 + nf * 16 + lr;
      bf[nf] = *(const short8*)(Bk0 + row * 32 + ((lc ^ ((row >> 1) & 3)) * 8));
    }
#pragma unroll
    for (int mf = 0; mf < 4; mf++) {
      const int row = wm * 128 + mf * 16 + lr;
      af[mf] = *(const short8*)(Ak0 + row * 32 + ((lc ^ ((row >> 1) & 3)) * 8));
    }
    if (t + 1 < nt) STAGE(t + 1, 0);
    __builtin_amdgcn_s_barrier();
    asm volatile("s_waitcnt lgkmcnt(0)" ::: "memory");
    __builtin_amdgcn_sched_barrier(0);
    __builtin_amdgcn_s_setprio(1);
#pragma unroll
    for (int mf = 0; mf < 4; mf++)
#pragma unroll
      for (int nf = 0; nf < 3; nf++)
        acc[mf][nf] = mfma16(af[mf], bf[nf], acc[mf][nf]);
    __builtin_amdgcn_s_setprio(0);
    __builtin_amdgcn_s_barrier();

    // ---- P1
#pragma unroll
    for (int mf = 0; mf < 4; mf++) {
      const int row = wm * 128 + 64 + mf * 16 + lr;
      af[mf] = *(const short8*)(Ak0 + row * 32 + ((lc ^ ((row >> 1) & 3)) * 8));
    }
    if (t + 1 < nt) STAGE(t + 1, 1);
    __builtin_amdgcn_s_barrier();
    asm volatile("s_waitcnt lgkmcnt(0)" ::: "memory");
    __builtin_amdgcn_sched_barrier(0);
    __builtin_amdgcn_s_setprio(1);
#pragma unroll
    for (int mf = 0; mf < 4; mf++)
#pragma unroll
      for (int nf = 0; nf < 3; nf++)
        acc[4 + mf][nf] = mfma16(af[mf], bf[nf], acc[4 + mf][nf]);
    __builtin_amdgcn_s_setprio(0);
    if (t + 1 < nt) {
      asm volatile("s_waitcnt vmcnt(4)" ::: "memory");
    } else {
      asm volatile("s_waitcnt vmcnt(0)" ::: "memory");
    }
    __builtin_amdgcn_s_barrier();

    // ---- P2
#pragma unroll
    for (int nf = 0; nf < 3; nf++) {
      const int row = wn * 48 + nf * 16 + lr;
      bf[nf] = *(const short8*)(Bk1 + row * 32 + ((lc ^ ((row >> 1) & 3)) * 8));
    }
#pragma unroll
    for (int mf = 0; mf < 4; mf++) {
      const int row = wm * 128 + mf * 16 + lr;
      af[mf] = *(const short8*)(Ak1 + row * 32 + ((lc ^ ((row >> 1) & 3)) * 8));
    }
    if (t + 1 < nt) STAGE(t + 1, 2);
    __builtin_amdgcn_s_barrier();
    asm volatile("s_waitcnt lgkmcnt(0)" ::: "memory");
    __builtin_amdgcn_sched_barrier(0);
    __builtin_amdgcn_s_setprio(1);
#pragma unroll
    for (int mf = 0; mf < 4; mf++)
#pragma unroll
      for (int nf = 0; nf < 3; nf++)
        acc[mf][nf] = mfma16(af[mf], bf[nf], acc[mf][nf]);
    __builtin_amdgcn_s_setprio(0);
    __builtin_amdgcn_s_barrier();

    // ---- P3
#pragma unroll
    for (int mf = 0; mf < 4; mf++) {
      const int row = wm * 128 + 64 + mf * 16 + lr;
      af[mf] = *(const short8*)(Ak1 + row * 32 + ((lc ^ ((row >> 1) & 3)) * 8));
    }
    if (t + 1 < nt) STAGE(t + 1, 3);
    __builtin_amdgcn_s_barrier();
    asm volatile("s_waitcnt lgkmcnt(0)" ::: "memory");
    __builtin_amdgcn_sched_barrier(0);
    __builtin_amdgcn_s_setprio(1);
#pragma unroll
    for (int mf = 0; mf < 4; mf++)
#pragma unroll
      for (int nf = 0; nf < 3; nf++)
        acc[4 + mf][nf] = mfma16(af[mf], bf[nf], acc[4 + mf][nf]);
    __builtin_amdgcn_s_setprio(0);
    if (t + 1 < nt) {
      asm volatile("s_waitcnt vmcnt(4)" ::: "memory");
    }
    __builtin_amdgcn_s_barrier();
  }

#pragma unroll
  for (int mfp = 0; mfp < 8; mfp++) {
#pragma unroll
    for (int nf = 0; nf < 3; nf++) {
      const int row = bm * 256 + wm * 128 + mfp * 16 + lc * 4;
      const int col = bn * 192 + wn * 48 + nf * 16 + lr;
#pragma unroll
      for (int r = 0; r < 4; r++)
        C[(size_t)(row + r) * N + col] = f2b(acc[mfp][nf][r]);
    }
  }
}

// ---------------- flash attention (causal GQA) — R9 config (best: 76us) ----------------
__global__ __launch_bounds__(256, 2) void attn_k(const ushort_t* __restrict__ Qb,
                                                 const ushort_t* __restrict__ Kb,
                                                 const ushort_t* __restrict__ Vf,
                                                 ushort_t* __restrict__ Yb) {
  __shared__ __attribute__((aligned(16))) ushort_t Ks[2][64 * 128];  // 32 KB
  const int tid = threadIdx.x;
  const int lane = tid & 63;
  const int w = tid >> 6;
  const int lr = lane & 15, lc = lane >> 4;
  const int gy = blockIdx.y;
  const int h = gy;
  const int b = blockIdx.z;
  const int kh = h >> 2;
  const int qc = b ? (15 - ((blockIdx.x + gy) & 15)) : ((blockIdx.x + gy) & 15);
  const int q0w = qc * 128 + w * 32;

  const ushort_t* Qp = Qb + (size_t)(b * 16 + h) * T_ * D_;
  const ushort_t* Kp = Kb + (size_t)(b * 4 + kh) * T_ * D_;
  const ushort_t* Vfb = Vf + (size_t)(b * 4 + kh) * 262144;

  const int st_row = tid >> 4;
  const int st_slot = tid & 15;

  short8 qf[2][4];
#pragma unroll
  for (int f = 0; f < 2; f++)
#pragma unroll
    for (int c = 0; c < 4; c++)
      qf[f][c] = *(const short8*)(Qp + (size_t)(q0w + f * 16 + lr) * D_ + c * 32 + lc * 8);

  f32x4 o[2][8];
#pragma unroll
  for (int f = 0; f < 2; f++)
#pragma unroll
    for (int n = 0; n < 8; n++) o[f][n] = (f32x4)(0.0f);
  float m[2] = {-1e30f, -1e30f}, l[2] = {0.0f, 0.0f};

  const int nt = 2 * qc + 2;

#pragma unroll
  for (int i = 0; i < 4; i++) {
    int row = i * 16 + st_row;
    async16(Kp + (size_t)row * D_ + (((st_slot - row) & 15) * 8),
            &Ks[0][0] + row * 128 + st_slot * 8);
  }

#pragma unroll 1
  for (int ti = 0; ti < nt; ti++) {
    __syncthreads();
    const int kv0 = ti * 64;
    if (ti + 1 < nt) {
      const ushort_t* Kn = Kp + (size_t)(kv0 + 64) * D_;
      ushort_t* dst = &Ks[(ti + 1) & 1][0];
#pragma unroll
      for (int i = 0; i < 4; i++) {
        int row = i * 16 + st_row;
        async16(Kn + (size_t)row * D_ + (((st_slot - row) & 15) * 8),
                dst + row * 128 + st_slot * 8);
      }
    }
    if (kv0 > q0w + 31) continue;
    const ushort_t* Kl = &Ks[ti & 1][0];
    const ushort_t* Vt0 = Vfb + (size_t)(ti * 2) * 4096;
    short8 vr0[8];
#pragma unroll
    for (int n = 0; n < 8; n++)
      vr0[n] = *(const short8*)(Vt0 + n * 512 + lane * 8);
    f32x4 s[2][4];
#pragma unroll
    for (int f = 0; f < 2; f++)
#pragma unroll
      for (int kj = 0; kj < 4; kj++) s[f][kj] = (f32x4)(0.0f);
    __builtin_amdgcn_s_setprio(1);
#pragma unroll
    for (int c = 0; c < 4; c++) {
      short8 kf[4];
#pragma unroll
      for (int kj = 0; kj < 4; kj++)
        kf[kj] = *(const short8*)(Kl + (kj * 16 + lr) * 128 + (((c * 4 + lc + lr) & 15) * 8));
#pragma unroll
      for (int f = 0; f < 2; f++)
#pragma unroll
        for (int kj = 0; kj < 4; kj++)
          s[f][kj] = mfma16(kf[kj], qf[f][c], s[f][kj]);
    }
    __builtin_amdgcn_s_setprio(0);
    const ushort_t* Vt1 = Vfb + (size_t)(ti * 2 + 1) * 4096;
    short8 vr1[8];
#pragma unroll
    for (int n = 0; n < 8; n++)
      vr1[n] = *(const short8*)(Vt1 + n * 512 + lane * 8);
    const bool maskt = (kv0 + 63 > q0w);
    union { unsigned u[4]; short8 v; } pa0[2], pa1[2];
#pragma unroll
    for (int f = 0; f < 2; f++) {
      const int q = q0w + f * 16 + lr;
      float pv[16];
      float mx = -1e30f;
      if (maskt) {
#pragma unroll
        for (int kj = 0; kj < 4; kj++)
#pragma unroll
          for (int r = 0; r < 4; r++) {
            float a = s[f][kj][r];
            if (kv0 + kj * 16 + lc * 4 + r > q) a = -1e30f;
            pv[kj * 4 + r] = a;
            mx = fmaxf(mx, a);
          }
      } else {
#pragma unroll
        for (int kj = 0; kj < 4; kj++)
#pragma unroll
          for (int r = 0; r < 4; r++) {
            float a = s[f][kj][r];
            pv[kj * 4 + r] = a;
            mx = fmaxf(mx, a);
          }
      }
      mx = fmaxf(mx, __shfl_xor(mx, 16));
      mx = fmaxf(mx, __shfl_xor(mx, 32));
      const bool need = __any(mx > m[f] + 8.0f);
      const float mn = need ? fmaxf(m[f], mx) : m[f];
      float rs = 0.0f;
#pragma unroll
      for (int i = 0; i < 16; i++) {
        pv[i] = exp2f(pv[i] - mn);
        rs += pv[i];
      }
      rs += __shfl_xor(rs, 16);
      rs += __shfl_xor(rs, 32);
#pragma unroll
      for (int kj = 0; kj < 2; kj++) {
        pa0[f].u[kj * 2] = cvtpk(pv[kj * 4], pv[kj * 4 + 1]);
        pa0[f].u[kj * 2 + 1] = cvtpk(pv[kj * 4 + 2], pv[kj * 4 + 3]);
        pa1[f].u[kj * 2] = cvtpk(pv[8 + kj * 4], pv[8 + kj * 4 + 1]);
        pa1[f].u[kj * 2 + 1] = cvtpk(pv[8 + kj * 4 + 2], pv[8 + kj * 4 + 3]);
      }
      if (need) {
        float al = exp2f(m[f] - mn);
        m[f] = mn;
        l[f] = l[f] * al + rs;
        float alT[4];
#pragma unroll
        for (int r = 0; r < 4; r++)
          alT[r] = __shfl(al, (lane & 48) | (lc * 4 + r));
#pragma unroll
        for (int n = 0; n < 8; n++)
#pragma unroll
          for (int r = 0; r < 4; r++) o[f][n][r] *= alT[r];
      } else {
        l[f] += rs;
      }
    }
    __builtin_amdgcn_s_setprio(1);
#pragma unroll
    for (int n = 0; n < 8; n++) {
      o[0][n] = mfma16(pa0[0].v, vr0[n], o[0][n]);
      o[1][n] = mfma16(pa0[1].v, vr0[n], o[1][n]);
    }
#pragma unroll
    for (int n = 0; n < 8; n++) {
      o[0][n] = mfma16(pa1[0].v, vr1[n], o[0][n]);
      o[1][n] = mfma16(pa1[1].v, vr1[n], o[1][n]);
    }
    __builtin_amdgcn_s_setprio(0);
  }
#pragma unroll
  for (int f = 0; f < 2; f++) {
    float inv = 1.0f / l[f];
    float invT[4];
#pragma unroll
    for (int r = 0; r < 4; r++)
      invT[r] = __shfl(inv, (lane & 48) | (lc * 4 + r));
#pragma unroll
    for (int n = 0; n < 8; n++)
#pragma unroll
      for (int r = 0; r < 4; r++) {
        int qo = q0w + f * 16 + lc * 4 + r;
        int d = n * 16 + lr;
        Yb[(size_t)(b * T_ + qo) * 2048 + h * 128 + d] = f2b(o[f][n][r] * invT[r]);
      }
  }
}

// ---------------- launch ----------------

extern "C" void kernel_launch(void* const* d_in, const int* in_sizes, int n_in,
                              void* d_out, int out_size, void* d_ws, size_t ws_size,
                              hipStream_t stream) {
  (void)in_sizes; (void)n_in; (void)out_size; (void)ws_size;
  const float* x = (const float*)d_in[0];
  const float* wq = (const float*)d_in[1];
  const float* wkv = (const float*)d_in[2];
  const float* wproj = (const float*)d_in[3];
  const float* omega = (const float*)d_in[4];
  float* out = (float*)d_out;
  char* ws = (char*)d_ws;

  ushort_t* xb     = (ushort_t*)(ws + 0);          // 4096x2048 bf16 = 16.8MB
  ushort_t* wqkvT  = (ushort_t*)(ws + 16777216);   // [3072][2048] bf16 (wqT then wkvT)
  ushort_t* wprojT = (ushort_t*)(ws + 29360128);   // 2048x2048 bf16
  ushort_t* QKVraw = (ushort_t*)(ws + 37748736);   // 4096x3072 bf16 = 25.2MB
  ushort_t* Qb     = (ushort_t*)(ws + 62914560);   // [b][h][t][d] bf16
  ushort_t* Kb     = (ushort_t*)(ws + 79691776);   // [b][kh][t][d] bf16
  ushort_t* Vf     = (ushort_t*)(ws + 83886080);   // V fragment-packed, 4MB
  ushort_t* Yb     = (ushort_t*)(ws + 88080384);   // 4096x2048 bf16
  float2*   tab    = (float2*)(ws + 104857600);    // 2048x64 float2 = 1MB

  convert_f32_bf16<<<8192, 256, 0, stream>>>(x, xb, 2097152);
  transpose_w3<<<dim3(64, 64, 3), dim3(32, 8), 0, stream>>>(wq, wkv, wproj, wqkvT, wprojT);
  rope_tab_k<<<512, 256, 0, stream>>>(omega, tab);

  // merged QKV projection via 256x192 8-phase (256 blocks = 100% CU fill)
  gemm256q<<<256, 512, 0, stream>>>(xb, wqkvT, QKVraw, 4096, 3072, 2048);

  rope_q_k<<<4096, 256, 0, stream>>>(QKVraw, tab, Qb);
  rope_k_k<<<1024, 256, 0, stream>>>(QKVraw, tab, Kb);
  v_frag_k<<<1024, 256, 0, stream>>>(QKVraw, Vf);

  attn_k<<<dim3(16, 16, 2), 256, 0, stream>>>(Qb, Kb, Vf, Yb);

  // output projection via 2-phase 128^2 (best measured for this shape)
  gemm_bt<<<dim3(16, 32), 256, 0, stream>>>(Yb, wprojT, out, 4096, 2048, 2048);
}

// Round 17
// 206.263 us; speedup vs baseline: 1.0699x; 1.0374x over previous
//
#include <hip/hip_runtime.h>
#include <hip/hip_bf16.h>

#define B_ 2
#define T_ 2048
#define C_ 2048
#define H_ 16
#define KH_ 4
#define D_ 128

typedef unsigned short ushort_t;
typedef __attribute__((ext_vector_type(8))) short short8;
typedef __attribute__((ext_vector_type(4))) float f32x4;

#define RSQRT_D 0.08838834764831845f
#define L2E 1.4426950408889634f
// Q pre-scale: 1/sqrt(D) * log2(e)  ->  QK^T lands in log2 units, softmax is pure exp2
#define QSCALE (0.08838834764831845f * 1.4426950408889634f)

__device__ __forceinline__ ushort_t f2b(float f) {
  union { float f; unsigned u; } v; v.f = f;
  unsigned r = v.u + 0x7fffu + ((v.u >> 16) & 1u);
  return (ushort_t)(r >> 16);
}
__device__ __forceinline__ float b2f(ushort_t u) {
  union { unsigned u; float f; } v; v.u = ((unsigned)u) << 16;
  return v.f;
}

__device__ __forceinline__ f32x4 mfma16(short8 a, short8 b, f32x4 c) {
  return __builtin_amdgcn_mfma_f32_16x16x32_bf16(a, b, c, 0, 0, 0);
}

__device__ __forceinline__ void async16(const void* g, void* l) {
  __builtin_amdgcn_global_load_lds(
      (const __attribute__((address_space(1))) void*)g,
      (__attribute__((address_space(3))) void*)l, 16, 0, 0);
}

// packed f32x2 -> bf16x2 (RTNE); dst.lo = bf16(lo), dst.hi = bf16(hi)
__device__ __forceinline__ unsigned cvtpk(float lo, float hi) {
  unsigned r;
  asm volatile("v_cvt_pk_bf16_f32 %0, %1, %2" : "=v"(r) : "v"(lo), "v"(hi));
  return r;
}

// ---------------- fused prep A: convert x -> bf16 | 3 weight transposes | rope table ----
// blocks [0,8192): convert; [8192,18432): transposes (wq 4096, wkv 2048, wproj 4096);
// [18432,18944): cos/sin table.  All branches per-block uniform.
__global__ __launch_bounds__(256) void prep_a(const float* __restrict__ x,
                                              const float* __restrict__ wq,
                                              const float* __restrict__ wkv,
                                              const float* __restrict__ wproj,
                                              const float* __restrict__ omega,
                                              ushort_t* __restrict__ xb,
                                              ushort_t* __restrict__ wqkvT,
                                              ushort_t* __restrict__ wprojT,
                                              float2* __restrict__ tab) {
  __shared__ float tile[32][33];
  int blk = blockIdx.x;
  const int tid = threadIdx.x;
  if (blk < 8192) {  // convert x (2,097,152 float4 units)
    int i = blk * 256 + tid;
    float4 v = ((const float4*)x)[i];
    ushort4 o;
    o.x = f2b(v.x); o.y = f2b(v.y); o.z = f2b(v.z); o.w = f2b(v.w);
    ((ushort4*)xb)[i] = o;
    return;
  }
  blk -= 8192;
  if (blk < 10240) {  // weight transposes: out[c][r] = bf16(in[r][c])
    const float* in;
    ushort_t* out;
    int Cc, gx, gy;
    if (blk < 4096)      { in = wq;    out = wqkvT;               Cc = 2048; gx = blk & 63;  gy = blk >> 6; }
    else if (blk < 6144) { int b2 = blk - 4096; in = wkv;  out = wqkvT + 2048 * 2048; Cc = 1024; gx = b2 & 31; gy = b2 >> 5; }
    else                 { int b2 = blk - 6144; in = wproj; out = wprojT;             Cc = 2048; gx = b2 & 63; gy = b2 >> 6; }
    const int c0 = gx * 32, r0 = gy * 32;
    const int tx = tid & 31, ty = tid >> 5;
#pragma unroll
    for (int i = 0; i < 4; i++) {
      int r = ty + i * 8;
      tile[r][tx] = in[(size_t)(r0 + r) * Cc + c0 + tx];
    }
    __syncthreads();
#pragma unroll
    for (int i = 0; i < 4; i++) {
      int r = ty + i * 8;
      out[(size_t)(c0 + r) * 2048 + r0 + tx] = f2b(tile[tx][r]);
    }
    return;
  }
  blk -= 10240;
  {  // rope table (131072 entries)
    int idx = blk * 256 + tid;
    int d = idx & 63;
    int t = idx >> 6;
    float ang = (float)t * omega[d];
    tab[idx] = make_float2(cosf(ang), sinf(ang));
  }
}

// ---------------- fused prep B: rope-Q | rope-K | V fragment pre-pack ----
// blocks [0,4096): rope_q; [4096,5120): rope_k; [5120,6144): v_frag.
__global__ __launch_bounds__(256) void prep_b(const ushort_t* __restrict__ QKVraw,
                                              const float2* __restrict__ tab,
                                              ushort_t* __restrict__ Qb,
                                              ushort_t* __restrict__ Kb,
                                              ushort_t* __restrict__ Vf) {
  int blk = blockIdx.x;
  const int tid = threadIdx.x;
  if (blk < 4096) {  // rope Q (1,048,576 d4-units), pre-scaled by QSCALE
    int idx = blk * 256 + tid;
    int d4 = (idx & 15) * 4;
    int h = (idx >> 4) & 15;
    int t = (idx >> 8) & 2047;
    int b = idx >> 19;
    size_t in_off = (size_t)(b * 2048 + t) * 3072 + h * 128 + d4;
    ushort4 x1 = *(const ushort4*)(QKVraw + in_off);
    ushort4 x2 = *(const ushort4*)(QKVraw + in_off + 64);
    float4 csA = *(const float4*)(&tab[t * 64 + d4]);
    float4 csB = *(const float4*)(&tab[t * 64 + d4 + 2]);
    ushort4 o1, o2;
    o1.x = f2b((b2f(x1.x) * csA.x - b2f(x2.x) * csA.y) * QSCALE);
    o2.x = f2b((b2f(x1.x) * csA.y + b2f(x2.x) * csA.x) * QSCALE);
    o1.y = f2b((b2f(x1.y) * csA.z - b2f(x2.y) * csA.w) * QSCALE);
    o2.y = f2b((b2f(x1.y) * csA.w + b2f(x2.y) * csA.z) * QSCALE);
    o1.z = f2b((b2f(x1.z) * csB.x - b2f(x2.z) * csB.y) * QSCALE);
    o2.z = f2b((b2f(x1.z) * csB.y + b2f(x2.z) * csB.x) * QSCALE);
    o1.w = f2b((b2f(x1.w) * csB.z - b2f(x2.w) * csB.w) * QSCALE);
    o2.w = f2b((b2f(x1.w) * csB.w + b2f(x2.w) * csB.z) * QSCALE);
    size_t out_off = ((size_t)(b * 16 + h) * 2048 + t) * 128 + d4;
    *(ushort4*)(Qb + out_off) = o1;
    *(ushort4*)(Qb + out_off + 64) = o2;
    return;
  }
  if (blk < 5120) {  // rope K (262,144 d4-units)
    int idx = (blk - 4096) * 256 + tid;
    int d4 = (idx & 15) * 4;
    int kh = (idx >> 4) & 3;
    int t = (idx >> 6) & 2047;
    int b = idx >> 17;
    size_t in_off = (size_t)(b * 2048 + t) * 3072 + 2048 + kh * 128 + d4;
    ushort4 x1 = *(const ushort4*)(QKVraw + in_off);
    ushort4 x2 = *(const ushort4*)(QKVraw + in_off + 64);
    float4 csA = *(const float4*)(&tab[t * 64 + d4]);
    float4 csB = *(const float4*)(&tab[t * 64 + d4 + 2]);
    ushort4 o1, o2;
    o1.x = f2b(b2f(x1.x) * csA.x - b2f(x2.x) * csA.y);
    o2.x = f2b(b2f(x1.x) * csA.y + b2f(x2.x) * csA.x);
    o1.y = f2b(b2f(x1.y) * csA.z - b2f(x2.y) * csA.w);
    o2.y = f2b(b2f(x1.y) * csA.w + b2f(x2.y) * csA.z);
    o1.z = f2b(b2f(x1.z) * csB.x - b2f(x2.z) * csB.y);
    o2.z = f2b(b2f(x1.z) * csB.y + b2f(x2.z) * csB.x);
    o1.w = f2b(b2f(x1.w) * csB.z - b2f(x2.w) * csB.w);
    o2.w = f2b(b2f(x1.w) * csB.w + b2f(x2.w) * csB.z);
    size_t out_off = ((size_t)(b * 4 + kh) * 2048 + t) * 128 + d4;
    *(ushort4*)(Kb + out_off) = o1;
    *(ushort4*)(Kb + out_off + 64) = o2;
    return;
  }
  {  // V fragment pre-pack (262,144 short8 units)
    int idx = (blk - 5120) * 256 + tid;
    int lane = idx & 63;
    int n = (idx >> 6) & 7;
    int hv = (idx >> 9) & 1;
    int tile = (idx >> 10) & 31;
    int z = idx >> 15;  // b*4+kh
    int b = z >> 2, kh = z & 3;
    int lr = lane & 15, lc = lane >> 4;
    int d = n * 16 + lr;
    union { ushort_t u[8]; short8 v; } out;
#pragma unroll
    for (int j = 0; j < 8; j++) {
      int tw = j >> 1, par = j & 1;
      int kl = (hv * 2 + (tw >> 1)) * 16 + lc * 4 + 2 * (tw & 1) + par;
      int t = tile * 64 + kl;
      out.u[j] = QKVraw[(size_t)(b * 2048 + t) * 3072 + 2560 + kh * 128 + d];
    }
    *(short8*)(Vf + (size_t)idx * 8) = out.v;
  }
}

__device__ __forceinline__ void store_out(float* C, size_t idx, float v) { C[idx] = v; }
__device__ __forceinline__ void store_out(ushort_t* C, size_t idx, float v) { C[idx] = f2b(v); }

// ---------------- GEMM 128x128 (proj): 2-phase dbuf, counted vmcnt (best for this shape) ---

template <typename OUT_T>
__global__ __launch_bounds__(256) void gemm_bt(const ushort_t* __restrict__ A,
                                               const ushort_t* __restrict__ Bt,
                                               OUT_T* __restrict__ C,
                                               int M, int N, int K) {
  __shared__ __attribute__((aligned(16))) ushort_t As[2][128 * 32];
  __shared__ __attribute__((aligned(16))) ushort_t Bs[2][128 * 32];
  const int tid = threadIdx.x;
  const int lane = tid & 63;
  const int w = tid >> 6;
  const int bm = blockIdx.y, bn = blockIdx.x;
  const int lr = lane & 15, lc = lane >> 4;
  const int wr = (w >> 1) * 64, wc = (w & 1) * 64;
  const ushort_t* Ab = A + (size_t)bm * 128 * K;
  const ushort_t* Bb = Bt + (size_t)bn * 128 * K;
  const int srow = tid >> 2;
  const int scol = (tid & 3) * 8;
  f32x4 acc[4][4];
#pragma unroll
  for (int i = 0; i < 4; i++)
#pragma unroll
    for (int j = 0; j < 4; j++) acc[i][j] = (f32x4)(0.0f);

  async16(Ab + (size_t)srow * K + scol, &As[0][0] + srow * 32 + scol);
  async16(Ab + (size_t)(srow + 64) * K + scol, &As[0][0] + (srow + 64) * 32 + scol);
  async16(Bb + (size_t)srow * K + scol, &Bs[0][0] + srow * 32 + scol);
  async16(Bb + (size_t)(srow + 64) * K + scol, &Bs[0][0] + (srow + 64) * 32 + scol);

  const int nt = K >> 5;
#pragma unroll 2
  for (int t = 0; t < nt - 1; t++) {
    const int cur = t & 1;
    {
      const int k1 = (t + 1) << 5;
      ushort_t* Ad = &As[cur ^ 1][0];
      ushort_t* Bd = &Bs[cur ^ 1][0];
      async16(Ab + (size_t)srow * K + k1 + scol, Ad + srow * 32 + scol);
      async16(Ab + (size_t)(srow + 64) * K + k1 + scol, Ad + (srow + 64) * 32 + scol);
      async16(Bb + (size_t)srow * K + k1 + scol, Bd + srow * 32 + scol);
      async16(Bb + (size_t)(srow + 64) * K + k1 + scol, Bd + (srow + 64) * 32 + scol);
    }
    asm volatile("s_waitcnt vmcnt(4)" ::: "memory");
    __builtin_amdgcn_s_barrier();
    __builtin_amdgcn_sched_barrier(0);
    const ushort_t* Al = &As[cur][0];
    const ushort_t* Bl = &Bs[cur][0];
    short8 af[4], bf[4];
#pragma unroll
    for (int mi = 0; mi < 4; mi++)
      af[mi] = *(const short8*)(Al + (wr + mi * 16 + lr) * 32 + lc * 8);
#pragma unroll
    for (int ni = 0; ni < 4; ni++)
      bf[ni] = *(const short8*)(Bl + (wc + ni * 16 + lr) * 32 + lc * 8);
#pragma unroll
    for (int mi = 0; mi < 4; mi++)
#pragma unroll
      for (int ni = 0; ni < 4; ni++)
        acc[mi][ni] = mfma16(af[mi], bf[ni], acc[mi][ni]);
    asm volatile("" ::: "memory");
    __builtin_amdgcn_s_barrier();
    asm volatile("" ::: "memory");
  }
  {
    const int cur = (nt - 1) & 1;
    asm volatile("s_waitcnt vmcnt(0)" ::: "memory");
    __builtin_amdgcn_s_barrier();
    __builtin_amdgcn_sched_barrier(0);
    const ushort_t* Al = &As[cur][0];
    const ushort_t* Bl = &Bs[cur][0];
    short8 af[4], bf[4];
#pragma unroll
    for (int mi = 0; mi < 4; mi++)
      af[mi] = *(const short8*)(Al + (wr + mi * 16 + lr) * 32 + lc * 8);
#pragma unroll
    for (int ni = 0; ni < 4; ni++)
      bf[ni] = *(const short8*)(Bl + (wc + ni * 16 + lr) * 32 + lc * 8);
#pragma unroll
    for (int mi = 0; mi < 4; mi++)
#pragma unroll
      for (int ni = 0; ni < 4; ni++)
        acc[mi][ni] = mfma16(af[mi], bf[ni], acc[mi][ni]);
  }
#pragma unroll
  for (int mi = 0; mi < 4; mi++) {
#pragma unroll
    for (int ni = 0; ni < 4; ni++) {
      int row = bm * 128 + wr + mi * 16 + lc * 4;
      int col = bn * 128 + wc + ni * 16 + lr;
#pragma unroll
      for (int r = 0; r < 4; r++)
        store_out(C, (size_t)(row + r) * N + col, acc[mi][ni][r]);
    }
  }
}

// ---------------- GEMM 256x192 8-phase (QKV): counted vmcnt(4), 100% CU fill ----
__global__ __launch_bounds__(512, 1) void gemm256q(const ushort_t* __restrict__ A,
                                                   const ushort_t* __restrict__ Bt,
                                                   ushort_t* __restrict__ C,
                                                   int M, int N, int K) {
  __shared__ __attribute__((aligned(16))) ushort_t As[2][2][8192];
  __shared__ __attribute__((aligned(16))) ushort_t Bs[2][2][6144];
  __shared__ __attribute__((aligned(16))) ushort_t Scr[512];
  const int tid = threadIdx.x;
  const int lane = tid & 63;
  const int w = tid >> 6;          // 0..7
  const int lr = lane & 15, lc = lane >> 4;
  const int wm = w >> 2, wn = w & 3;
  const int nwg = gridDim.x;
  const int cpx = nwg >> 3;
  const int swz = (blockIdx.x & 7) * cpx + (blockIdx.x >> 3);
  const int bnc = N / 192;
  const int bm = swz / bnc, bn = swz % bnc;
  const ushort_t* Ab = A + (size_t)bm * 256 * K;
  const ushort_t* Bb = Bt + (size_t)bn * 192 * K;

  f32x4 acc[8][3];
#pragma unroll
  for (int i = 0; i < 8; i++)
#pragma unroll
    for (int j = 0; j < 3; j++) acc[i][j] = (f32x4)(0.0f);

  auto STAGE = [&](int kt, int hid) {
    const int buf = kt & 1;
    const int kk = hid >> 1;
    const int kbase = kt * 64 + kk * 32;
    if (!(hid & 1)) {
      ushort_t* db = &As[buf][kk][0];
      {
        const int u = tid, row = u >> 2, c = u & 3;
        const int lch = c ^ ((row >> 1) & 3);
        async16(Ab + (size_t)row * K + kbase + lch * 8, db + u * 8);
      }
      {
        const int u = 512 + tid, row = u >> 2, c = u & 3;
        const int lch = c ^ ((row >> 1) & 3);
        async16(Ab + (size_t)row * K + kbase + lch * 8, db + u * 8);
      }
    } else {
      ushort_t* db = &Bs[buf][kk][0];
      {
        const int u = tid, row = u >> 2, c = u & 3;
        const int lch = c ^ ((row >> 1) & 3);
        async16(Bb + (size_t)row * K + kbase + lch * 8, db + u * 8);
      }
      if (tid < 256) {
        const int u = 512 + tid, row = u >> 2, c = u & 3;
        const int lch = c ^ ((row >> 1) & 3);
        async16(Bb + (size_t)row * K + kbase + lch * 8, db + u * 8);
      } else {
        async16(Bb + (size_t)(tid & 255) * 8, &Scr[0]);
      }
    }
  };

  const int nt = K >> 6;
  STAGE(0, 0); STAGE(0, 1); STAGE(0, 2); STAGE(0, 3);
  asm volatile("s_waitcnt vmcnt(4)" ::: "memory");
  __builtin_amdgcn_s_barrier();

#pragma unroll 1
  for (int t = 0; t < nt; ++t) {
    const int buf = t & 1;
    const ushort_t* Ak0 = &As[buf][0][0];
    const ushort_t* Ak1 = &As[buf][1][0];
    const ushort_t* Bk0 = &Bs[buf][0][0];
    const ushort_t* Bk1 = &Bs[buf][1][0];
    short8 af[4], bf[3];

    // ---- P0
#pragma unroll
    for (int nf = 0; nf < 3; nf++) {
      const int row = wn * 48 + nf * 16 + lr;
      bf[nf] = *(const short8*)(Bk0 + row * 32 + ((lc ^ ((row >> 1) & 3)) * 8));
    }
#pragma unroll
    for (int mf = 0; mf < 4; mf++) {
      const int row = wm * 128 + mf * 16 + lr;
      af[mf] = *(const short8*)(Ak0 + row * 32 + ((lc ^ ((row >> 1) & 3)) * 8));
    }
    if (t + 1 < nt) STAGE(t + 1, 0);
    __builtin_amdgcn_s_barrier();
    asm volatile("s_waitcnt lgkmcnt(0)" ::: "memory");
    __builtin_amdgcn_sched_barrier(0);
    __builtin_amdgcn_s_setprio(1);
#pragma unroll
    for (int mf = 0; mf < 4; mf++)
#pragma unroll
      for (int nf = 0; nf < 3; nf++)
        acc[mf][nf] = mfma16(af[mf], bf[nf], acc[mf][nf]);
    __builtin_amdgcn_s_setprio(0);
    __builtin_amdgcn_s_barrier();

    // ---- P1
#pragma unroll
    for (int mf = 0; mf < 4; mf++) {
      const int row = wm * 128 + 64 + mf * 16 + lr;
      af[mf] = *(const short8*)(Ak0 + row * 32 + ((lc ^ ((row >> 1) & 3)) * 8));
    }
    if (t + 1 < nt) STAGE(t + 1, 1);
    __builtin_amdgcn_s_barrier();
    asm volatile("s_waitcnt lgkmcnt(0)" ::: "memory");
    __builtin_amdgcn_sched_barrier(0);
    __builtin_amdgcn_s_setprio(1);
#pragma unroll
    for (int mf = 0; mf < 4; mf++)
#pragma unroll
      for (int nf = 0; nf < 3; nf++)
        acc[4 + mf][nf] = mfma16(af[mf], bf[nf], acc[4 + mf][nf]);
    __builtin_amdgcn_s_setprio(0);
    if (t + 1 < nt) {
      asm volatile("s_waitcnt vmcnt(4)" ::: "memory");
    } else {
      asm volatile("s_waitcnt vmcnt(0)" ::: "memory");
    }
    __builtin_amdgcn_s_barrier();

    // ---- P2
#pragma unroll
    for (int nf = 0; nf < 3; nf++) {
      const int row = wn * 48 + nf * 16 + lr;
      bf[nf] = *(const short8*)(Bk1 + row * 32 + ((lc ^ ((row >> 1) & 3)) * 8));
    }
#pragma unroll
    for (int mf = 0; mf < 4; mf++) {
      const int row = wm * 128 + mf * 16 + lr;
      af[mf] = *(const short8*)(Ak1 + row * 32 + ((lc ^ ((row >> 1) & 3)) * 8));
    }
    if (t + 1 < nt) STAGE(t + 1, 2);
    __builtin_amdgcn_s_barrier();
    asm volatile("s_waitcnt lgkmcnt(0)" ::: "memory");
    __builtin_amdgcn_sched_barrier(0);
    __builtin_amdgcn_s_setprio(1);
#pragma unroll
    for (int mf = 0; mf < 4; mf++)
#pragma unroll
      for (int nf = 0; nf < 3; nf++)
        acc[mf][nf] = mfma16(af[mf], bf[nf], acc[mf][nf]);
    __builtin_amdgcn_s_setprio(0);
    __builtin_amdgcn_s_barrier();

    // ---- P3
#pragma unroll
    for (int mf = 0; mf < 4; mf++) {
      const int row = wm * 128 + 64 + mf * 16 + lr;
      af[mf] = *(const short8*)(Ak1 + row * 32 + ((lc ^ ((row >> 1) & 3)) * 8));
    }
    if (t + 1 < nt) STAGE(t + 1, 3);
    __builtin_amdgcn_s_barrier();
    asm volatile("s_waitcnt lgkmcnt(0)" ::: "memory");
    __builtin_amdgcn_sched_barrier(0);
    __builtin_amdgcn_s_setprio(1);
#pragma unroll
    for (int mf = 0; mf < 4; mf++)
#pragma unroll
      for (int nf = 0; nf < 3; nf++)
        acc[4 + mf][nf] = mfma16(af[mf], bf[nf], acc[4 + mf][nf]);
    __builtin_amdgcn_s_setprio(0);
    if (t + 1 < nt) {
      asm volatile("s_waitcnt vmcnt(4)" ::: "memory");
    }
    __builtin_amdgcn_s_barrier();
  }

#pragma unroll
  for (int mfp = 0; mfp < 8; mfp++) {
#pragma unroll
    for (int nf = 0; nf < 3; nf++) {
      const int row = bm * 256 + wm * 128 + mfp * 16 + lc * 4;
      const int col = bn * 192 + wn * 48 + nf * 16 + lr;
#pragma unroll
      for (int r = 0; r < 4; r++)
        C[(size_t)(row + r) * N + col] = f2b(acc[mfp][nf][r]);
    }
  }
}

// ---------------- flash attention (causal GQA) — R9 config (best: 76us) ----------------
__global__ __launch_bounds__(256, 2) void attn_k(const ushort_t* __restrict__ Qb,
                                                 const ushort_t* __restrict__ Kb,
                                                 const ushort_t* __restrict__ Vf,
                                                 ushort_t* __restrict__ Yb) {
  __shared__ __attribute__((aligned(16))) ushort_t Ks[2][64 * 128];  // 32 KB
  const int tid = threadIdx.x;
  const int lane = tid & 63;
  const int w = tid >> 6;
  const int lr = lane & 15, lc = lane >> 4;
  const int gy = blockIdx.y;
  const int h = gy;
  const int b = blockIdx.z;
  const int kh = h >> 2;
  const int qc = b ? (15 - ((blockIdx.x + gy) & 15)) : ((blockIdx.x + gy) & 15);
  const int q0w = qc * 128 + w * 32;

  const ushort_t* Qp = Qb + (size_t)(b * 16 + h) * T_ * D_;
  const ushort_t* Kp = Kb + (size_t)(b * 4 + kh) * T_ * D_;
  const ushort_t* Vfb = Vf + (size_t)(b * 4 + kh) * 262144;

  const int st_row = tid >> 4;
  const int st_slot = tid & 15;

  short8 qf[2][4];
#pragma unroll
  for (int f = 0; f < 2; f++)
#pragma unroll
    for (int c = 0; c < 4; c++)
      qf[f][c] = *(const short8*)(Qp + (size_t)(q0w + f * 16 + lr) * D_ + c * 32 + lc * 8);

  f32x4 o[2][8];
#pragma unroll
  for (int f = 0; f < 2; f++)
#pragma unroll
    for (int n = 0; n < 8; n++) o[f][n] = (f32x4)(0.0f);
  float m[2] = {-1e30f, -1e30f}, l[2] = {0.0f, 0.0f};

  const int nt = 2 * qc + 2;

#pragma unroll
  for (int i = 0; i < 4; i++) {
    int row = i * 16 + st_row;
    async16(Kp + (size_t)row * D_ + (((st_slot - row) & 15) * 8),
            &Ks[0][0] + row * 128 + st_slot * 8);
  }

#pragma unroll 1
  for (int ti = 0; ti < nt; ti++) {
    __syncthreads();
    const int kv0 = ti * 64;
    if (ti + 1 < nt) {
      const ushort_t* Kn = Kp + (size_t)(kv0 + 64) * D_;
      ushort_t* dst = &Ks[(ti + 1) & 1][0];
#pragma unroll
      for (int i = 0; i < 4; i++) {
        int row = i * 16 + st_row;
        async16(Kn + (size_t)row * D_ + (((st_slot - row) & 15) * 8),
                dst + row * 128 + st_slot * 8);
      }
    }
    if (kv0 > q0w + 31) continue;
    const ushort_t* Kl = &Ks[ti & 1][0];
    const ushort_t* Vt0 = Vfb + (size_t)(ti * 2) * 4096;
    short8 vr0[8];
#pragma unroll
    for (int n = 0; n < 8; n++)
      vr0[n] = *(const short8*)(Vt0 + n * 512 + lane * 8);
    f32x4 s[2][4];
#pragma unroll
    for (int f = 0; f < 2; f++)
#pragma unroll
      for (int kj = 0; kj < 4; kj++) s[f][kj] = (f32x4)(0.0f);
    __builtin_amdgcn_s_setprio(1);
#pragma unroll
    for (int c = 0; c < 4; c++) {
      short8 kf[4];
#pragma unroll
      for (int kj = 0; kj < 4; kj++)
        kf[kj] = *(const short8*)(Kl + (kj * 16 + lr) * 128 + (((c * 4 + lc + lr) & 15) * 8));
#pragma unroll
      for (int f = 0; f < 2; f++)
#pragma unroll
        for (int kj = 0; kj < 4; kj++)
          s[f][kj] = mfma16(kf[kj], qf[f][c], s[f][kj]);
    }
    __builtin_amdgcn_s_setprio(0);
    const ushort_t* Vt1 = Vfb + (size_t)(ti * 2 + 1) * 4096;
    short8 vr1[8];
#pragma unroll
    for (int n = 0; n < 8; n++)
      vr1[n] = *(const short8*)(Vt1 + n * 512 + lane * 8);
    const bool maskt = (kv0 + 63 > q0w);
    union { unsigned u[4]; short8 v; } pa0[2], pa1[2];
#pragma unroll
    for (int f = 0; f < 2; f++) {
      const int q = q0w + f * 16 + lr;
      float pv[16];
      float mx = -1e30f;
      if (maskt) {
#pragma unroll
        for (int kj = 0; kj < 4; kj++)
#pragma unroll
          for (int r = 0; r < 4; r++) {
            float a = s[f][kj][r];
            if (kv0 + kj * 16 + lc * 4 + r > q) a = -1e30f;
            pv[kj * 4 + r] = a;
            mx = fmaxf(mx, a);
          }
      } else {
#pragma unroll
        for (int kj = 0; kj < 4; kj++)
#pragma unroll
          for (int r = 0; r < 4; r++) {
            float a = s[f][kj][r];
            pv[kj * 4 + r] = a;
            mx = fmaxf(mx, a);
          }
      }
      mx = fmaxf(mx, __shfl_xor(mx, 16));
      mx = fmaxf(mx, __shfl_xor(mx, 32));
      const bool need = __any(mx > m[f] + 8.0f);
      const float mn = need ? fmaxf(m[f], mx) : m[f];
      float rs = 0.0f;
#pragma unroll
      for (int i = 0; i < 16; i++) {
        pv[i] = exp2f(pv[i] - mn);
        rs += pv[i];
      }
      rs += __shfl_xor(rs, 16);
      rs += __shfl_xor(rs, 32);
#pragma unroll
      for (int kj = 0; kj < 2; kj++) {
        pa0[f].u[kj * 2] = cvtpk(pv[kj * 4], pv[kj * 4 + 1]);
        pa0[f].u[kj * 2 + 1] = cvtpk(pv[kj * 4 + 2], pv[kj * 4 + 3]);
        pa1[f].u[kj * 2] = cvtpk(pv[8 + kj * 4], pv[8 + kj * 4 + 1]);
        pa1[f].u[kj * 2 + 1] = cvtpk(pv[8 + kj * 4 + 2], pv[8 + kj * 4 + 3]);
      }
      if (need) {
        float al = exp2f(m[f] - mn);
        m[f] = mn;
        l[f] = l[f] * al + rs;
        float alT[4];
#pragma unroll
        for (int r = 0; r < 4; r++)
          alT[r] = __shfl(al, (lane & 48) | (lc * 4 + r));
#pragma unroll
        for (int n = 0; n < 8; n++)
#pragma unroll
          for (int r = 0; r < 4; r++) o[f][n][r] *= alT[r];
      } else {
        l[f] += rs;
      }
    }
    __builtin_amdgcn_s_setprio(1);
#pragma unroll
    for (int n = 0; n < 8; n++) {
      o[0][n] = mfma16(pa0[0].v, vr0[n], o[0][n]);
      o[1][n] = mfma16(pa0[1].v, vr0[n], o[1][n]);
    }
#pragma unroll
    for (int n = 0; n < 8; n++) {
      o[0][n] = mfma16(pa1[0].v, vr1[n], o[0][n]);
      o[1][n] = mfma16(pa1[1].v, vr1[n], o[1][n]);
    }
    __builtin_amdgcn_s_setprio(0);
  }
#pragma unroll
  for (int f = 0; f < 2; f++) {
    float inv = 1.0f / l[f];
    float invT[4];
#pragma unroll
    for (int r = 0; r < 4; r++)
      invT[r] = __shfl(inv, (lane & 48) | (lc * 4 + r));
#pragma unroll
    for (int n = 0; n < 8; n++)
#pragma unroll
      for (int r = 0; r < 4; r++) {
        int qo = q0w + f * 16 + lc * 4 + r;
        int d = n * 16 + lr;
        Yb[(size_t)(b * T_ + qo) * 2048 + h * 128 + d] = f2b(o[f][n][r] * invT[r]);
      }
  }
}

// ---------------- launch ----------------

extern "C" void kernel_launch(void* const* d_in, const int* in_sizes, int n_in,
                              void* d_out, int out_size, void* d_ws, size_t ws_size,
                              hipStream_t stream) {
  (void)in_sizes; (void)n_in; (void)out_size; (void)ws_size;
  const float* x = (const float*)d_in[0];
  const float* wq = (const float*)d_in[1];
  const float* wkv = (const float*)d_in[2];
  const float* wproj = (const float*)d_in[3];
  const float* omega = (const float*)d_in[4];
  float* out = (float*)d_out;
  char* ws = (char*)d_ws;

  ushort_t* xb     = (ushort_t*)(ws + 0);          // 4096x2048 bf16 = 16.8MB
  ushort_t* wqkvT  = (ushort_t*)(ws + 16777216);   // [3072][2048] bf16 (wqT then wkvT)
  ushort_t* wprojT = (ushort_t*)(ws + 29360128);   // 2048x2048 bf16
  ushort_t* QKVraw = (ushort_t*)(ws + 37748736);   // 4096x3072 bf16 = 25.2MB
  ushort_t* Qb     = (ushort_t*)(ws + 62914560);   // [b][h][t][d] bf16
  ushort_t* Kb     = (ushort_t*)(ws + 79691776);   // [b][kh][t][d] bf16
  ushort_t* Vf     = (ushort_t*)(ws + 83886080);   // V fragment-packed, 4MB
  ushort_t* Yb     = (ushort_t*)(ws + 88080384);   // 4096x2048 bf16
  float2*   tab    = (float2*)(ws + 104857600);    // 2048x64 float2 = 1MB

  // fused prep: convert | 3 transposes | rope table
  prep_a<<<18944, 256, 0, stream>>>(x, wq, wkv, wproj, omega, xb, wqkvT, wprojT, tab);

  // merged QKV projection via 256x192 8-phase (256 blocks = 100% CU fill)
  gemm256q<<<256, 512, 0, stream>>>(xb, wqkvT, QKVraw, 4096, 3072, 2048);

  // fused prep: rope-Q | rope-K | V fragment pre-pack
  prep_b<<<6144, 256, 0, stream>>>(QKVraw, tab, Qb, Kb, Vf);

  attn_k<<<dim3(16, 16, 2), 256, 0, stream>>>(Qb, Kb, Vf, Yb);

  // output projection via 2-phase 128^2 (best measured for this shape)
  gemm_bt<<<dim3(16, 32), 256, 0, stream>>>(Yb, wprojT, out, 4096, 2048, 2048);
}

// Round 18
// 203.786 us; speedup vs baseline: 1.0829x; 1.0122x over previous
//
#include <hip/hip_runtime.h>
#include <hip/hip_bf16.h>

#define B_ 2
#define T_ 2048
#define C_ 2048
#define H_ 16
#define KH_ 4
#define D_ 128

typedef unsigned short ushort_t;
typedef __attribute__((ext_vector_type(8))) short short8;
typedef __attribute__((ext_vector_type(4))) float f32x4;

#define RSQRT_D 0.08838834764831845f
#define L2E 1.4426950408889634f
// Q pre-scale: 1/sqrt(D) * log2(e)  ->  QK^T lands in log2 units, softmax is pure exp2
#define QSCALE (0.08838834764831845f * 1.4426950408889634f)

__device__ __forceinline__ ushort_t f2b(float f) {
  union { float f; unsigned u; } v; v.f = f;
  unsigned r = v.u + 0x7fffu + ((v.u >> 16) & 1u);
  return (ushort_t)(r >> 16);
}
__device__ __forceinline__ float b2f(ushort_t u) {
  union { unsigned u; float f; } v; v.u = ((unsigned)u) << 16;
  return v.f;
}

__device__ __forceinline__ f32x4 mfma16(short8 a, short8 b, f32x4 c) {
  return __builtin_amdgcn_mfma_f32_16x16x32_bf16(a, b, c, 0, 0, 0);
}

__device__ __forceinline__ void async16(const void* g, void* l) {
  __builtin_amdgcn_global_load_lds(
      (const __attribute__((address_space(1))) void*)g,
      (__attribute__((address_space(3))) void*)l, 16, 0, 0);
}

// packed f32x2 -> bf16x2 (RTNE); dst.lo = bf16(lo), dst.hi = bf16(hi)
__device__ __forceinline__ unsigned cvtpk(float lo, float hi) {
  unsigned r;
  asm volatile("v_cvt_pk_bf16_f32 %0, %1, %2" : "=v"(r) : "v"(lo), "v"(hi));
  return r;
}

// ---------------- fused prep A: convert x -> bf16 | 3 weight transposes | rope table ----
__global__ __launch_bounds__(256) void prep_a(const float* __restrict__ x,
                                              const float* __restrict__ wq,
                                              const float* __restrict__ wkv,
                                              const float* __restrict__ wproj,
                                              const float* __restrict__ omega,
                                              ushort_t* __restrict__ xb,
                                              ushort_t* __restrict__ wqkvT,
                                              ushort_t* __restrict__ wprojT,
                                              float2* __restrict__ tab) {
  __shared__ float tile[32][33];
  int blk = blockIdx.x;
  const int tid = threadIdx.x;
  if (blk < 8192) {  // convert x (2,097,152 float4 units)
    int i = blk * 256 + tid;
    float4 v = ((const float4*)x)[i];
    ushort4 o;
    o.x = f2b(v.x); o.y = f2b(v.y); o.z = f2b(v.z); o.w = f2b(v.w);
    ((ushort4*)xb)[i] = o;
    return;
  }
  blk -= 8192;
  if (blk < 10240) {  // weight transposes: out[c][r] = bf16(in[r][c])
    const float* in;
    ushort_t* out;
    int Cc, gx, gy;
    if (blk < 4096)      { in = wq;    out = wqkvT;               Cc = 2048; gx = blk & 63;  gy = blk >> 6; }
    else if (blk < 6144) { int b2 = blk - 4096; in = wkv;  out = wqkvT + 2048 * 2048; Cc = 1024; gx = b2 & 31; gy = b2 >> 5; }
    else                 { int b2 = blk - 6144; in = wproj; out = wprojT;             Cc = 2048; gx = b2 & 63; gy = b2 >> 6; }
    const int c0 = gx * 32, r0 = gy * 32;
    const int tx = tid & 31, ty = tid >> 5;
#pragma unroll
    for (int i = 0; i < 4; i++) {
      int r = ty + i * 8;
      tile[r][tx] = in[(size_t)(r0 + r) * Cc + c0 + tx];
    }
    __syncthreads();
#pragma unroll
    for (int i = 0; i < 4; i++) {
      int r = ty + i * 8;
      out[(size_t)(c0 + r) * 2048 + r0 + tx] = f2b(tile[tx][r]);
    }
    return;
  }
  blk -= 10240;
  {  // rope table (131072 entries)
    int idx = blk * 256 + tid;
    int d = idx & 63;
    int t = idx >> 6;
    float ang = (float)t * omega[d];
    tab[idx] = make_float2(cosf(ang), sinf(ang));
  }
}

// ---------------- fused prep B: rope-Q | rope-K | V fragment pre-pack ----
__global__ __launch_bounds__(256) void prep_b(const ushort_t* __restrict__ QKVraw,
                                              const float2* __restrict__ tab,
                                              ushort_t* __restrict__ Qb,
                                              ushort_t* __restrict__ Kb,
                                              ushort_t* __restrict__ Vf) {
  int blk = blockIdx.x;
  const int tid = threadIdx.x;
  if (blk < 4096) {  // rope Q, pre-scaled by QSCALE
    int idx = blk * 256 + tid;
    int d4 = (idx & 15) * 4;
    int h = (idx >> 4) & 15;
    int t = (idx >> 8) & 2047;
    int b = idx >> 19;
    size_t in_off = (size_t)(b * 2048 + t) * 3072 + h * 128 + d4;
    ushort4 x1 = *(const ushort4*)(QKVraw + in_off);
    ushort4 x2 = *(const ushort4*)(QKVraw + in_off + 64);
    float4 csA = *(const float4*)(&tab[t * 64 + d4]);
    float4 csB = *(const float4*)(&tab[t * 64 + d4 + 2]);
    ushort4 o1, o2;
    o1.x = f2b((b2f(x1.x) * csA.x - b2f(x2.x) * csA.y) * QSCALE);
    o2.x = f2b((b2f(x1.x) * csA.y + b2f(x2.x) * csA.x) * QSCALE);
    o1.y = f2b((b2f(x1.y) * csA.z - b2f(x2.y) * csA.w) * QSCALE);
    o2.y = f2b((b2f(x1.y) * csA.w + b2f(x2.y) * csA.z) * QSCALE);
    o1.z = f2b((b2f(x1.z) * csB.x - b2f(x2.z) * csB.y) * QSCALE);
    o2.z = f2b((b2f(x1.z) * csB.y + b2f(x2.z) * csB.x) * QSCALE);
    o1.w = f2b((b2f(x1.w) * csB.z - b2f(x2.w) * csB.w) * QSCALE);
    o2.w = f2b((b2f(x1.w) * csB.w + b2f(x2.w) * csB.z) * QSCALE);
    size_t out_off = ((size_t)(b * 16 + h) * 2048 + t) * 128 + d4;
    *(ushort4*)(Qb + out_off) = o1;
    *(ushort4*)(Qb + out_off + 64) = o2;
    return;
  }
  if (blk < 5120) {  // rope K
    int idx = (blk - 4096) * 256 + tid;
    int d4 = (idx & 15) * 4;
    int kh = (idx >> 4) & 3;
    int t = (idx >> 6) & 2047;
    int b = idx >> 17;
    size_t in_off = (size_t)(b * 2048 + t) * 3072 + 2048 + kh * 128 + d4;
    ushort4 x1 = *(const ushort4*)(QKVraw + in_off);
    ushort4 x2 = *(const ushort4*)(QKVraw + in_off + 64);
    float4 csA = *(const float4*)(&tab[t * 64 + d4]);
    float4 csB = *(const float4*)(&tab[t * 64 + d4 + 2]);
    ushort4 o1, o2;
    o1.x = f2b(b2f(x1.x) * csA.x - b2f(x2.x) * csA.y);
    o2.x = f2b(b2f(x1.x) * csA.y + b2f(x2.x) * csA.x);
    o1.y = f2b(b2f(x1.y) * csA.z - b2f(x2.y) * csA.w);
    o2.y = f2b(b2f(x1.y) * csA.w + b2f(x2.y) * csA.z);
    o1.z = f2b(b2f(x1.z) * csB.x - b2f(x2.z) * csB.y);
    o2.z = f2b(b2f(x1.z) * csB.y + b2f(x2.z) * csB.x);
    o1.w = f2b(b2f(x1.w) * csB.z - b2f(x2.w) * csB.w);
    o2.w = f2b(b2f(x1.w) * csB.w + b2f(x2.w) * csB.z);
    size_t out_off = (size_t)(b * 4 + kh) * 2048 * 128 + (size_t)t * 128 + d4;
    *(ushort4*)(Kb + out_off) = o1;
    *(ushort4*)(Kb + out_off + 64) = o2;
    return;
  }
  {  // V fragment pre-pack
    int idx = (blk - 5120) * 256 + tid;
    int lane = idx & 63;
    int n = (idx >> 6) & 7;
    int hv = (idx >> 9) & 1;
    int tile = (idx >> 10) & 31;
    int z = idx >> 15;  // b*4+kh
    int b = z >> 2, kh = z & 3;
    int lr = lane & 15, lc = lane >> 4;
    int d = n * 16 + lr;
    union { ushort_t u[8]; short8 v; } out;
#pragma unroll
    for (int j = 0; j < 8; j++) {
      int tw = j >> 1, par = j & 1;
      int kl = (hv * 2 + (tw >> 1)) * 16 + lc * 4 + 2 * (tw & 1) + par;
      int t = tile * 64 + kl;
      out.u[j] = QKVraw[(size_t)(b * 2048 + t) * 3072 + 2560 + kh * 128 + d];
    }
    *(short8*)(Vf + (size_t)idx * 8) = out.v;
  }
}

// ---------------- GEMM 128x256 2-phase-per-Ktile (proj, f32 out): 16 MFMA/phase ----
// BM=128, BN=256, BK=64 as k0/k1. Grid 32x8 = 256 blocks = 100% CU fill.
// 8 waves (2M x 4N): per-wave 64x64 output (acc[4][4]). LDS 96KB + pad.
// Phase = { 8 ds_read (4 af + 4 bf, k published last phase) ; STAGE next
// k-half (A:1 + B:2 loads/thread) ; barrier ; lgkmcnt(0) ; setprio 16 MFMA ;
// vmcnt(3) ; barrier }.  vmcnt(3): per phase-end outstanding = current(3) +
// next(3) halves; retiring to 3 publishes the half the NEXT phase reads.
// Prologue 6 loads -> vmcnt(3) publishes k0. Tail: vmcnt(0) at last P0.
// Swizzle chunk = lc ^ ((row>>1)&3) with pre-swizzled source (both-sides).
__global__ __launch_bounds__(512, 1) void gemm_proj(const ushort_t* __restrict__ A,
                                                    const ushort_t* __restrict__ Bt,
                                                    float* __restrict__ C,
                                                    int M, int N, int K) {
  __shared__ __attribute__((aligned(16))) ushort_t As[2][2][4096];   // [buf][kk][128*32]
  __shared__ __attribute__((aligned(16))) ushort_t Bs[2][2][8192];   // [buf][kk][256*32]
  const int tid = threadIdx.x;
  const int lane = tid & 63;
  const int w = tid >> 6;          // 0..7
  const int lr = lane & 15, lc = lane >> 4;
  const int wm = w >> 2, wn = w & 3;
  // XCD-aware bijective swizzle over 1D grid (256 % 8 == 0)
  const int nwg = gridDim.x;
  const int cpx = nwg >> 3;
  const int swz = (blockIdx.x & 7) * cpx + (blockIdx.x >> 3);
  const int bnc = N >> 8;          // N/256
  const int bm = swz / bnc, bn = swz % bnc;
  const ushort_t* Ab = A + (size_t)bm * 128 * K;
  const ushort_t* Bb = Bt + (size_t)bn * 256 * K;

  f32x4 acc[4][4];
#pragma unroll
  for (int i = 0; i < 4; i++)
#pragma unroll
    for (int j = 0; j < 4; j++) acc[i][j] = (f32x4)(0.0f);

  // stage one k-half (kk) of tile kt: A 512 units (1 ld/thr) + B 1024 units (2 ld/thr)
  auto STAGE = [&](int kt, int kk) {
    const int buf = kt & 1;
    const int kbase = kt * 64 + kk * 32;
    {
      ushort_t* db = &As[buf][kk][0];
      const int u = tid, row = u >> 2, c = u & 3;
      const int lch = c ^ ((row >> 1) & 3);
      async16(Ab + (size_t)row * K + kbase + lch * 8, db + u * 8);
    }
    {
      ushort_t* db = &Bs[buf][kk][0];
      {
        const int u = tid, row = u >> 2, c = u & 3;
        const int lch = c ^ ((row >> 1) & 3);
        async16(Bb + (size_t)row * K + kbase + lch * 8, db + u * 8);
      }
      {
        const int u = 512 + tid, row = u >> 2, c = u & 3;
        const int lch = c ^ ((row >> 1) & 3);
        async16(Bb + (size_t)row * K + kbase + lch * 8, db + u * 8);
      }
    }
  };

  const int nt = K >> 6;
  // prologue: stage tile0 k0 + k1 (6 loads); vmcnt(3) publishes k0
  STAGE(0, 0); STAGE(0, 1);
  asm volatile("s_waitcnt vmcnt(3)" ::: "memory");
  __builtin_amdgcn_s_barrier();

#pragma unroll 1
  for (int t = 0; t < nt; ++t) {
    const int buf = t & 1;
#pragma unroll
    for (int kk = 0; kk < 2; kk++) {
      const ushort_t* Ak = &As[buf][kk][0];
      const ushort_t* Bk = &Bs[buf][kk][0];
      short8 af[4], bf[4];
#pragma unroll
      for (int mf = 0; mf < 4; mf++) {
        const int row = wm * 64 + mf * 16 + lr;
        af[mf] = *(const short8*)(Ak + row * 32 + ((lc ^ ((row >> 1) & 3)) * 8));
      }
#pragma unroll
      for (int nf = 0; nf < 4; nf++) {
        const int row = wn * 64 + nf * 16 + lr;
        bf[nf] = *(const short8*)(Bk + row * 32 + ((lc ^ ((row >> 1) & 3)) * 8));
      }
      if (t + 1 < nt) STAGE(t + 1, kk);
      __builtin_amdgcn_s_barrier();
      asm volatile("s_waitcnt lgkmcnt(0)" ::: "memory");
      __builtin_amdgcn_sched_barrier(0);
      __builtin_amdgcn_s_setprio(1);
#pragma unroll
      for (int mf = 0; mf < 4; mf++)
#pragma unroll
        for (int nf = 0; nf < 4; nf++)
          acc[mf][nf] = mfma16(af[mf], bf[nf], acc[mf][nf]);
      __builtin_amdgcn_s_setprio(0);
      // publish the half the next phase reads
      if (t + 1 < nt) {
        asm volatile("s_waitcnt vmcnt(3)" ::: "memory");
      } else if (kk == 0) {
        asm volatile("s_waitcnt vmcnt(0)" ::: "memory");
      }
      __builtin_amdgcn_s_barrier();
    }
  }

#pragma unroll
  for (int mf = 0; mf < 4; mf++) {
#pragma unroll
    for (int nf = 0; nf < 4; nf++) {
      const int row = bm * 128 + wm * 64 + mf * 16 + lc * 4;
      const int col = bn * 256 + wn * 64 + nf * 16 + lr;
#pragma unroll
      for (int r = 0; r < 4; r++)
        C[(size_t)(row + r) * N + col] = acc[mf][nf][r];
    }
  }
}

// ---------------- GEMM 256x192 8-phase (QKV): counted vmcnt(4), 100% CU fill ----
__global__ __launch_bounds__(512, 1) void gemm256q(const ushort_t* __restrict__ A,
                                                   const ushort_t* __restrict__ Bt,
                                                   ushort_t* __restrict__ C,
                                                   int M, int N, int K) {
  __shared__ __attribute__((aligned(16))) ushort_t As[2][2][8192];
  __shared__ __attribute__((aligned(16))) ushort_t Bs[2][2][6144];
  __shared__ __attribute__((aligned(16))) ushort_t Scr[512];
  const int tid = threadIdx.x;
  const int lane = tid & 63;
  const int w = tid >> 6;          // 0..7
  const int lr = lane & 15, lc = lane >> 4;
  const int wm = w >> 2, wn = w & 3;
  const int nwg = gridDim.x;
  const int cpx = nwg >> 3;
  const int swz = (blockIdx.x & 7) * cpx + (blockIdx.x >> 3);
  const int bnc = N / 192;
  const int bm = swz / bnc, bn = swz % bnc;
  const ushort_t* Ab = A + (size_t)bm * 256 * K;
  const ushort_t* Bb = Bt + (size_t)bn * 192 * K;

  f32x4 acc[8][3];
#pragma unroll
  for (int i = 0; i < 8; i++)
#pragma unroll
    for (int j = 0; j < 3; j++) acc[i][j] = (f32x4)(0.0f);

  auto STAGE = [&](int kt, int hid) {
    const int buf = kt & 1;
    const int kk = hid >> 1;
    const int kbase = kt * 64 + kk * 32;
    if (!(hid & 1)) {
      ushort_t* db = &As[buf][kk][0];
      {
        const int u = tid, row = u >> 2, c = u & 3;
        const int lch = c ^ ((row >> 1) & 3);
        async16(Ab + (size_t)row * K + kbase + lch * 8, db + u * 8);
      }
      {
        const int u = 512 + tid, row = u >> 2, c = u & 3;
        const int lch = c ^ ((row >> 1) & 3);
        async16(Ab + (size_t)row * K + kbase + lch * 8, db + u * 8);
      }
    } else {
      ushort_t* db = &Bs[buf][kk][0];
      {
        const int u = tid, row = u >> 2, c = u & 3;
        const int lch = c ^ ((row >> 1) & 3);
        async16(Bb + (size_t)row * K + kbase + lch * 8, db + u * 8);
      }
      if (tid < 256) {
        const int u = 512 + tid, row = u >> 2, c = u & 3;
        const int lch = c ^ ((row >> 1) & 3);
        async16(Bb + (size_t)row * K + kbase + lch * 8, db + u * 8);
      } else {
        async16(Bb + (size_t)(tid & 255) * 8, &Scr[0]);
      }
    }
  };

  const int nt = K >> 6;
  STAGE(0, 0); STAGE(0, 1); STAGE(0, 2); STAGE(0, 3);
  asm volatile("s_waitcnt vmcnt(4)" ::: "memory");
  __builtin_amdgcn_s_barrier();

#pragma unroll 1
  for (int t = 0; t < nt; ++t) {
    const int buf = t & 1;
    const ushort_t* Ak0 = &As[buf][0][0];
    const ushort_t* Ak1 = &As[buf][1][0];
    const ushort_t* Bk0 = &Bs[buf][0][0];
    const ushort_t* Bk1 = &Bs[buf][1][0];
    short8 af[4], bf[3];

    // ---- P0
#pragma unroll
    for (int nf = 0; nf < 3; nf++) {
      const int row = wn * 48 + nf * 16 + lr;
      bf[nf] = *(const short8*)(Bk0 + row * 32 + ((lc ^ ((row >> 1) & 3)) * 8));
    }
#pragma unroll
    for (int mf = 0; mf < 4; mf++) {
      const int row = wm * 128 + mf * 16 + lr;
      af[mf] = *(const short8*)(Ak0 + row * 32 + ((lc ^ ((row >> 1) & 3)) * 8));
    }
    if (t + 1 < nt) STAGE(t + 1, 0);
    __builtin_amdgcn_s_barrier();
    asm volatile("s_waitcnt lgkmcnt(0)" ::: "memory");
    __builtin_amdgcn_sched_barrier(0);
    __builtin_amdgcn_s_setprio(1);
#pragma unroll
    for (int mf = 0; mf < 4; mf++)
#pragma unroll
      for (int nf = 0; nf < 3; nf++)
        acc[mf][nf] = mfma16(af[mf], bf[nf], acc[mf][nf]);
    __builtin_amdgcn_s_setprio(0);
    __builtin_amdgcn_s_barrier();

    // ---- P1
#pragma unroll
    for (int mf = 0; mf < 4; mf++) {
      const int row = wm * 128 + 64 + mf * 16 + lr;
      af[mf] = *(const short8*)(Ak0 + row * 32 + ((lc ^ ((row >> 1) & 3)) * 8));
    }
    if (t + 1 < nt) STAGE(t + 1, 1);
    __builtin_amdgcn_s_barrier();
    asm volatile("s_waitcnt lgkmcnt(0)" ::: "memory");
    __builtin_amdgcn_sched_barrier(0);
    __builtin_amdgcn_s_setprio(1);
#pragma unroll
    for (int mf = 0; mf < 4; mf++)
#pragma unroll
      for (int nf = 0; nf < 3; nf++)
        acc[4 + mf][nf] = mfma16(af[mf], bf[nf], acc[4 + mf][nf]);
    __builtin_amdgcn_s_setprio(0);
    if (t + 1 < nt) {
      asm volatile("s_waitcnt vmcnt(4)" ::: "memory");
    } else {
      asm volatile("s_waitcnt vmcnt(0)" ::: "memory");
    }
    __builtin_amdgcn_s_barrier();

    // ---- P2
#pragma unroll
    for (int nf = 0; nf < 3; nf++) {
      const int row = wn * 48 + nf * 16 + lr;
      bf[nf] = *(const short8*)(Bk1 + row * 32 + ((lc ^ ((row >> 1) & 3)) * 8));
    }
#pragma unroll
    for (int mf = 0; mf < 4; mf++) {
      const int row = wm * 128 + mf * 16 + lr;
      af[mf] = *(const short8*)(Ak1 + row * 32 + ((lc ^ ((row >> 1) & 3)) * 8));
    }
    if (t + 1 < nt) STAGE(t + 1, 2);
    __builtin_amdgcn_s_barrier();
    asm volatile("s_waitcnt lgkmcnt(0)" ::: "memory");
    __builtin_amdgcn_sched_barrier(0);
    __builtin_amdgcn_s_setprio(1);
#pragma unroll
    for (int mf = 0; mf < 4; mf++)
#pragma unroll
      for (int nf = 0; nf < 3; nf++)
        acc[mf][nf] = mfma16(af[mf], bf[nf], acc[mf][nf]);
    __builtin_amdgcn_s_setprio(0);
    __builtin_amdgcn_s_barrier();

    // ---- P3
#pragma unroll
    for (int mf = 0; mf < 4; mf++) {
      const int row = wm * 128 + 64 + mf * 16 + lr;
      af[mf] = *(const short8*)(Ak1 + row * 32 + ((lc ^ ((row >> 1) & 3)) * 8));
    }
    if (t + 1 < nt) STAGE(t + 1, 3);
    __builtin_amdgcn_s_barrier();
    asm volatile("s_waitcnt lgkmcnt(0)" ::: "memory");
    __builtin_amdgcn_sched_barrier(0);
    __builtin_amdgcn_s_setprio(1);
#pragma unroll
    for (int mf = 0; mf < 4; mf++)
#pragma unroll
      for (int nf = 0; nf < 3; nf++)
        acc[4 + mf][nf] = mfma16(af[mf], bf[nf], acc[4 + mf][nf]);
    __builtin_amdgcn_s_setprio(0);
    if (t + 1 < nt) {
      asm volatile("s_waitcnt vmcnt(4)" ::: "memory");
    }
    __builtin_amdgcn_s_barrier();
  }

#pragma unroll
  for (int mfp = 0; mfp < 8; mfp++) {
#pragma unroll
    for (int nf = 0; nf < 3; nf++) {
      const int row = bm * 256 + wm * 128 + mfp * 16 + lc * 4;
      const int col = bn * 192 + wn * 48 + nf * 16 + lr;
#pragma unroll
      for (int r = 0; r < 4; r++)
        C[(size_t)(row + r) * N + col] = f2b(acc[mfp][nf][r]);
    }
  }
}

// ---------------- flash attention (causal GQA) — R9 config (best: 76us) ----------------
__global__ __launch_bounds__(256, 2) void attn_k(const ushort_t* __restrict__ Qb,
                                                 const ushort_t* __restrict__ Kb,
                                                 const ushort_t* __restrict__ Vf,
                                                 ushort_t* __restrict__ Yb) {
  __shared__ __attribute__((aligned(16))) ushort_t Ks[2][64 * 128];  // 32 KB
  const int tid = threadIdx.x;
  const int lane = tid & 63;
  const int w = tid >> 6;
  const int lr = lane & 15, lc = lane >> 4;
  const int gy = blockIdx.y;
  const int h = gy;
  const int b = blockIdx.z;
  const int kh = h >> 2;
  const int qc = b ? (15 - ((blockIdx.x + gy) & 15)) : ((blockIdx.x + gy) & 15);
  const int q0w = qc * 128 + w * 32;

  const ushort_t* Qp = Qb + (size_t)(b * 16 + h) * T_ * D_;
  const ushort_t* Kp = Kb + (size_t)(b * 4 + kh) * T_ * D_;
  const ushort_t* Vfb = Vf + (size_t)(b * 4 + kh) * 262144;

  const int st_row = tid >> 4;
  const int st_slot = tid & 15;

  short8 qf[2][4];
#pragma unroll
  for (int f = 0; f < 2; f++)
#pragma unroll
    for (int c = 0; c < 4; c++)
      qf[f][c] = *(const short8*)(Qp + (size_t)(q0w + f * 16 + lr) * D_ + c * 32 + lc * 8);

  f32x4 o[2][8];
#pragma unroll
  for (int f = 0; f < 2; f++)
#pragma unroll
    for (int n = 0; n < 8; n++) o[f][n] = (f32x4)(0.0f);
  float m[2] = {-1e30f, -1e30f}, l[2] = {0.0f, 0.0f};

  const int nt = 2 * qc + 2;

#pragma unroll
  for (int i = 0; i < 4; i++) {
    int row = i * 16 + st_row;
    async16(Kp + (size_t)row * D_ + (((st_slot - row) & 15) * 8),
            &Ks[0][0] + row * 128 + st_slot * 8);
  }

#pragma unroll 1
  for (int ti = 0; ti < nt; ti++) {
    __syncthreads();
    const int kv0 = ti * 64;
    if (ti + 1 < nt) {
      const ushort_t* Kn = Kp + (size_t)(kv0 + 64) * D_;
      ushort_t* dst = &Ks[(ti + 1) & 1][0];
#pragma unroll
      for (int i = 0; i < 4; i++) {
        int row = i * 16 + st_row;
        async16(Kn + (size_t)row * D_ + (((st_slot - row) & 15) * 8),
                dst + row * 128 + st_slot * 8);
      }
    }
    if (kv0 > q0w + 31) continue;
    const ushort_t* Kl = &Ks[ti & 1][0];
    const ushort_t* Vt0 = Vfb + (size_t)(ti * 2) * 4096;
    short8 vr0[8];
#pragma unroll
    for (int n = 0; n < 8; n++)
      vr0[n] = *(const short8*)(Vt0 + n * 512 + lane * 8);
    f32x4 s[2][4];
#pragma unroll
    for (int f = 0; f < 2; f++)
#pragma unroll
      for (int kj = 0; kj < 4; kj++) s[f][kj] = (f32x4)(0.0f);
    __builtin_amdgcn_s_setprio(1);
#pragma unroll
    for (int c = 0; c < 4; c++) {
      short8 kf[4];
#pragma unroll
      for (int kj = 0; kj < 4; kj++)
        kf[kj] = *(const short8*)(Kl + (kj * 16 + lr) * 128 + (((c * 4 + lc + lr) & 15) * 8));
#pragma unroll
      for (int f = 0; f < 2; f++)
#pragma unroll
        for (int kj = 0; kj < 4; kj++)
          s[f][kj] = mfma16(kf[kj], qf[f][c], s[f][kj]);
    }
    __builtin_amdgcn_s_setprio(0);
    const ushort_t* Vt1 = Vfb + (size_t)(ti * 2 + 1) * 4096;
    short8 vr1[8];
#pragma unroll
    for (int n = 0; n < 8; n++)
      vr1[n] = *(const short8*)(Vt1 + n * 512 + lane * 8);
    const bool maskt = (kv0 + 63 > q0w);
    union { unsigned u[4]; short8 v; } pa0[2], pa1[2];
#pragma unroll
    for (int f = 0; f < 2; f++) {
      const int q = q0w + f * 16 + lr;
      float pv[16];
      float mx = -1e30f;
      if (maskt) {
#pragma unroll
        for (int kj = 0; kj < 4; kj++)
#pragma unroll
          for (int r = 0; r < 4; r++) {
            float a = s[f][kj][r];
            if (kv0 + kj * 16 + lc * 4 + r > q) a = -1e30f;
            pv[kj * 4 + r] = a;
            mx = fmaxf(mx, a);
          }
      } else {
#pragma unroll
        for (int kj = 0; kj < 4; kj++)
#pragma unroll
          for (int r = 0; r < 4; r++) {
            float a = s[f][kj][r];
            pv[kj * 4 + r] = a;
            mx = fmaxf(mx, a);
          }
      }
      mx = fmaxf(mx, __shfl_xor(mx, 16));
      mx = fmaxf(mx, __shfl_xor(mx, 32));
      const bool need = __any(mx > m[f] + 8.0f);
      const float mn = need ? fmaxf(m[f], mx) : m[f];
      float rs = 0.0f;
#pragma unroll
      for (int i = 0; i < 16; i++) {
        pv[i] = exp2f(pv[i] - mn);
        rs += pv[i];
      }
      rs += __shfl_xor(rs, 16);
      rs += __shfl_xor(rs, 32);
#pragma unroll
      for (int kj = 0; kj < 2; kj++) {
        pa0[f].u[kj * 2] = cvtpk(pv[kj * 4], pv[kj * 4 + 1]);
        pa0[f].u[kj * 2 + 1] = cvtpk(pv[kj * 4 + 2], pv[kj * 4 + 3]);
        pa1[f].u[kj * 2] = cvtpk(pv[8 + kj * 4], pv[8 + kj * 4 + 1]);
        pa1[f].u[kj * 2 + 1] = cvtpk(pv[8 + kj * 4 + 2], pv[8 + kj * 4 + 3]);
      }
      if (need) {
        float al = exp2f(m[f] - mn);
        m[f] = mn;
        l[f] = l[f] * al + rs;
        float alT[4];
#pragma unroll
        for (int r = 0; r < 4; r++)
          alT[r] = __shfl(al, (lane & 48) | (lc * 4 + r));
#pragma unroll
        for (int n = 0; n < 8; n++)
#pragma unroll
          for (int r = 0; r < 4; r++) o[f][n][r] *= alT[r];
      } else {
        l[f] += rs;
      }
    }
    __builtin_amdgcn_s_setprio(1);
#pragma unroll
    for (int n = 0; n < 8; n++) {
      o[0][n] = mfma16(pa0[0].v, vr0[n], o[0][n]);
      o[1][n] = mfma16(pa0[1].v, vr0[n], o[1][n]);
    }
#pragma unroll
    for (int n = 0; n < 8; n++) {
      o[0][n] = mfma16(pa1[0].v, vr1[n], o[0][n]);
      o[1][n] = mfma16(pa1[1].v, vr1[n], o[1][n]);
    }
    __builtin_amdgcn_s_setprio(0);
  }
#pragma unroll
  for (int f = 0; f < 2; f++) {
    float inv = 1.0f / l[f];
    float invT[4];
#pragma unroll
    for (int r = 0; r < 4; r++)
      invT[r] = __shfl(inv, (lane & 48) | (lc * 4 + r));
#pragma unroll
    for (int n = 0; n < 8; n++)
#pragma unroll
      for (int r = 0; r < 4; r++) {
        int qo = q0w + f * 16 + lc * 4 + r;
        int d = n * 16 + lr;
        Yb[(size_t)(b * T_ + qo) * 2048 + h * 128 + d] = f2b(o[f][n][r] * invT[r]);
      }
  }
}

// ---------------- launch ----------------

extern "C" void kernel_launch(void* const* d_in, const int* in_sizes, int n_in,
                              void* d_out, int out_size, void* d_ws, size_t ws_size,
                              hipStream_t stream) {
  (void)in_sizes; (void)n_in; (void)out_size; (void)ws_size;
  const float* x = (const float*)d_in[0];
  const float* wq = (const float*)d_in[1];
  const float* wkv = (const float*)d_in[2];
  const float* wproj = (const float*)d_in[3];
  const float* omega = (const float*)d_in[4];
  float* out = (float*)d_out;
  char* ws = (char*)d_ws;

  ushort_t* xb     = (ushort_t*)(ws + 0);          // 4096x2048 bf16 = 16.8MB
  ushort_t* wqkvT  = (ushort_t*)(ws + 16777216);   // [3072][2048] bf16 (wqT then wkvT)
  ushort_t* wprojT = (ushort_t*)(ws + 29360128);   // 2048x2048 bf16
  ushort_t* QKVraw = (ushort_t*)(ws + 37748736);   // 4096x3072 bf16 = 25.2MB
  ushort_t* Qb     = (ushort_t*)(ws + 62914560);   // [b][h][t][d] bf16
  ushort_t* Kb     = (ushort_t*)(ws + 79691776);   // [b][kh][t][d] bf16
  ushort_t* Vf     = (ushort_t*)(ws + 83886080);   // V fragment-packed, 4MB
  ushort_t* Yb     = (ushort_t*)(ws + 88080384);   // 4096x2048 bf16
  float2*   tab    = (float2*)(ws + 104857600);    // 2048x64 float2 = 1MB

  // fused prep: convert | 3 transposes | rope table
  prep_a<<<18944, 256, 0, stream>>>(x, wq, wkv, wproj, omega, xb, wqkvT, wprojT, tab);

  // merged QKV projection via 256x192 8-phase (256 blocks = 100% CU fill)
  gemm256q<<<256, 512, 0, stream>>>(xb, wqkvT, QKVraw, 4096, 3072, 2048);

  // fused prep: rope-Q | rope-K | V fragment pre-pack
  prep_b<<<6144, 256, 0, stream>>>(QKVraw, tab, Qb, Kb, Vf);

  attn_k<<<dim3(16, 16, 2), 256, 0, stream>>>(Qb, Kb, Vf, Yb);

  // output projection via 128x256 2-phase-per-Ktile (256 blocks, 16 MFMA/phase)
  gemm_proj<<<256, 512, 0, stream>>>(Yb, wprojT, out, 4096, 2048, 2048);
}